// Round 6
// baseline (23848.616 us; speedup 1.0000x reference)
//
#include <hip/hip_runtime.h>

#define TL 2048

typedef __attribute__((ext_vector_type(8))) short bfx8;
typedef __attribute__((ext_vector_type(4))) float fx4;

__device__ __forceinline__ float sigf(float x){ return __builtin_amdgcn_rcpf(1.0f + __expf(-x)); }
__device__ __forceinline__ float tanhff(float x){ return fmaf(2.0f, sigf(2.0f*x), -1.0f); }

template<int CTRL>
__device__ __forceinline__ float dpp_xadd(float v){
  int s = __builtin_amdgcn_update_dpp(0, __float_as_int(v), CTRL, 0xF, 0xF, true);
  return v + __int_as_float(s);
}
__device__ __forceinline__ float swz4_add(float v){
  int s = __builtin_amdgcn_ds_swizzle(__float_as_int(v), 0x101F);
  return v + __int_as_float(s);
}
__device__ __forceinline__ float bperm(float v, int srclane){
  return __int_as_float(__builtin_amdgcn_ds_bpermute(srclane << 2, __float_as_int(v)));
}
__device__ __forceinline__ unsigned short f2bf(float f){   // RNE fp32->bf16
  unsigned int u = __float_as_uint(f);
  u += 0x7fffu + ((u >> 16) & 1u);
  return (unsigned short)(u >> 16);
}
__device__ __forceinline__ float dot4(float4 a, float4 b, float acc){
  acc = fmaf(a.x, b.x, acc); acc = fmaf(a.y, b.y, acc);
  acc = fmaf(a.z, b.z, acc); acc = fmaf(a.w, b.w, acc);
  return acc;
}
// LDS-only barrier: do NOT drain vmcnt (global h-stores stay in flight).
__device__ __forceinline__ void barrier_lgkm(){
  asm volatile("s_waitcnt lgkmcnt(0)\ns_barrier" ::: "memory");
}
__device__ __forceinline__ bfx8 pack8(const float* p){
  bfx8 r;
  #pragma unroll
  for (int i = 0; i < 8; ++i) r[i] = (short)f2bf(p[i]);
  return r;
}

// Uber-kernel; segments selected per-block by [nL1 | nL2 | nL3]:
//   blockIdx [0,nL1)         : L1 scan, 16 chains/WG via MFMA, 2-product
//                              (h split hi+lo bf16, Whh1 plain bf16)
//   blockIdx [nL1,nL1+nL2)   : L2 scan, Wih2 proj via MFMA 16-step lookahead
//   blockIdx [nL1+nL2,+nL3)  : L3 scan, Wih3 proj via MFMA + T-mean accumulate
// Round-6 L1 fixes: (1) H stride 136->132 shorts. 132 shorts = 66 dwords,
// 66 % 32 = 2 -> lane m's b128 starts at bank 2m (16 distinct even banks,
// 2 touches/bank = HW floor). The old 136 (68 dwords, = 4 mod 32) aliased
// lanes m and m+8 onto the same 4-bank group (PMC: +4.2M conflict cyc).
// (2) hi/lo accumulators split: 8 independent 4-deep MFMA chains instead
// of 4 x 8-deep (dep distance 8 issue slots > MFMA latency).
__global__ __launch_bounds__(512, 2) void mega_kernel(
    int nL1, int nL2, int nL3, int cb1, int cb2, int cb3, int a1sz,
    int p1, int p2, int p3,
    const float* __restrict__ x,
    const float* __restrict__ Wih1, const float* __restrict__ Whh1,
    const float* __restrict__ bih1, const float* __restrict__ bhh1,
    const float* __restrict__ Wih2, const float* __restrict__ Whh2,
    const float* __restrict__ bih2, const float* __restrict__ bhh2,
    const float* __restrict__ Wih3, const float* __restrict__ Whh3,
    const float* __restrict__ bih3, const float* __restrict__ bhh3,
    unsigned short* __restrict__ h1r0, unsigned short* __restrict__ h1r1,
    unsigned short* __restrict__ o2r0, unsigned short* __restrict__ o2r1,
    float* __restrict__ sums)
{
  __shared__ __align__(16) unsigned char smem[34816];
  const int tid  = threadIdx.x;
  const int bid  = blockIdx.x;
  const int lane = tid & 63;
  const int wv   = tid >> 6;

  if (bid < nL1){
    // ============ L1: H=128, 16 chains (one dir) per WG, MFMA recurrence ===
    // pre[chain][n] = sum_k h[chain][k]*Whh[n][k], mfma_16x16x32_bf16:
    //   A: lane holds h[chain=lane&15][k=Kf*32+(lane>>4)*8+i]  (hi+lo bf16)
    //   B: lane holds bf16(Whh[n=g*128+wv*16+(lane&15)][same k])
    //   C: lane holds pre[chain=(lane>>4)*4+rr][n = wv*16+(lane&15)]
    // Layout proven correct (rounds 4/5: absmax identical to fp32 VALU).
    const int wgi = bid >> 1, dir = bid & 1;
    const int base = wgi * 16;
    const int nact = min(16, a1sz - base);
    unsigned short* h1o = p1 ? h1r1 : h1r0;
    const int m  = lane & 15;
    const int g8 = lane >> 4;
    const int hown = wv * 16 + m;

    // B-frags: 4 gates x 4 Kf x bfx8 = 64 VGPR.
    bfx8 Bf[4][4];
    const float* Wh = Whh1 + dir * 65536;
    #pragma unroll
    for (int g = 0; g < 4; ++g){
      #pragma unroll
      for (int Kf = 0; Kf < 4; ++Kf)
        Bf[g][Kf] = pack8(Wh + (g * 128 + hown) * 128 + Kf * 32 + g8 * 8);
    }
    // x-projection (D=2) and bias stay exact fp32 VALU.
    float xwA[4], xwB[4], bs[4];
    #pragma unroll
    for (int g = 0; g < 4; ++g){
      const int r = g * 128 + hown;
      xwA[g] = Wih1[dir * 1024 + r * 2];
      xwB[g] = Wih1[dir * 1024 + r * 2 + 1];
      bs[g]  = bih1[dir * 512 + r] + bhh1[dir * 512 + r];
    }
    // LDS: Hhi[2][16][132] s16 (8448 B) | Hlo same (8448) | xbuf[2][16][132]
    // f32 (16896). Total 33792 B.
    unsigned short* Hhi = (unsigned short*)smem;
    unsigned short* Hlo = Hhi + 4224;
    float* xbf = (float*)(smem + 16896);

    for (int i = tid; i < 4224; i += 512) ((unsigned int*)smem)[i] = 0u;

    // x streaming: 64-step windows, double-buffered, loaded 64 steps ahead.
    const int xc_ = tid >> 5, xo = tid & 31;
    const int xcb = min(xc_, nact - 1);               // clamp: no OOB reads
    const float* xbase = x + (size_t)(cb1 + base + xcb) * (TL * 2);
    auto loadX = [&](int w){
      const int ttb = dir ? (TL - 64 - w * 64) : (w * 64);
      return *(const float4*)(xbase + ttb * 2 + xo * 4);
    };
    auto storeX = [&](float4 v, int w){
      *(float4*)(xbf + (w & 1) * 2112 + xc_ * 132 + xo * 4) = v;
    };
    float4 xv = loadX(0);
    storeX(xv, 0);
    xv = loadX(1);
    __syncthreads();

    float cst0 = 0.f, cst1 = 0.f, cst2 = 0.f, cst3 = 0.f;
    for (int t = 0; t < TL; ++t){
      const int cur = t & 1;
      if ((t & 63) == 0){
        const int wn = (t >> 6) + 1;   // window wn: stored now, read at t+64
        if (wn < 32){
          storeX(xv, wn);
          if (wn + 1 < 32) xv = loadX(wn + 1);
        }
      }
      // 8 independent accumulators: hi-product and lo-product kept separate
      // so every MFMA chain is only 4 deep (Kf), issued round-robin.
      fx4 aH0 = {0.f,0.f,0.f,0.f}, aH1 = {0.f,0.f,0.f,0.f};
      fx4 aH2 = {0.f,0.f,0.f,0.f}, aH3 = {0.f,0.f,0.f,0.f};
      fx4 aL0 = {0.f,0.f,0.f,0.f}, aL1 = {0.f,0.f,0.f,0.f};
      fx4 aL2 = {0.f,0.f,0.f,0.f}, aL3 = {0.f,0.f,0.f,0.f};
      const int abase = cur * 2112 + m * 132 + g8 * 8;
      #pragma unroll
      for (int Kf = 0; Kf < 4; ++Kf){
        const bfx8 Ahi = *(const bfx8*)(Hhi + abase + Kf * 32);
        const bfx8 Alo = *(const bfx8*)(Hlo + abase + Kf * 32);
        aH0 = __builtin_amdgcn_mfma_f32_16x16x32_bf16(Ahi, Bf[0][Kf], aH0, 0,0,0);
        aH1 = __builtin_amdgcn_mfma_f32_16x16x32_bf16(Ahi, Bf[1][Kf], aH1, 0,0,0);
        aH2 = __builtin_amdgcn_mfma_f32_16x16x32_bf16(Ahi, Bf[2][Kf], aH2, 0,0,0);
        aH3 = __builtin_amdgcn_mfma_f32_16x16x32_bf16(Ahi, Bf[3][Kf], aH3, 0,0,0);
        aL0 = __builtin_amdgcn_mfma_f32_16x16x32_bf16(Alo, Bf[0][Kf], aL0, 0,0,0);
        aL1 = __builtin_amdgcn_mfma_f32_16x16x32_bf16(Alo, Bf[1][Kf], aL1, 0,0,0);
        aL2 = __builtin_amdgcn_mfma_f32_16x16x32_bf16(Alo, Bf[2][Kf], aL2, 0,0,0);
        aL3 = __builtin_amdgcn_mfma_f32_16x16x32_bf16(Alo, Bf[3][Kf], aL3, 0,0,0);
      }
      const int tt = dir ? (TL - 1 - t) : t;
      const float* xrow = xbf + ((t >> 6) & 1) * 2112 + (tt & 63) * 2;
      const int nxt = cur ^ 1;
      #pragma unroll
      for (int rr = 0; rr < 4; ++rr){
        const int ch = g8 * 4 + rr;
        const float2 xc = *(const float2*)(xrow + ch * 132); // broadcast read
        const float pi = (aH0[rr] + aL0[rr]) + fmaf(xwA[0], xc.x, fmaf(xwB[0], xc.y, bs[0]));
        const float pf = (aH1[rr] + aL1[rr]) + fmaf(xwA[1], xc.x, fmaf(xwB[1], xc.y, bs[1]));
        const float pg = (aH2[rr] + aL2[rr]) + fmaf(xwA[2], xc.x, fmaf(xwB[2], xc.y, bs[2]));
        const float po = (aH3[rr] + aL3[rr]) + fmaf(xwA[3], xc.x, fmaf(xwB[3], xc.y, bs[3]));
        const float ig = sigf(pi), fg = sigf(pf);
        const float gg = tanhff(pg), og = sigf(po);
        float& cr = (rr == 0 ? cst0 : rr == 1 ? cst1 : rr == 2 ? cst2 : cst3);
        cr = fmaf(fg, cr, ig * gg);
        const float h = og * tanhff(cr);
        const unsigned short hh = f2bf(h);
        const float hf2 = __uint_as_float((unsigned)hh << 16);
        const unsigned short hl = f2bf(h - hf2);
        Hhi[nxt * 2112 + ch * 132 + hown] = hh;
        Hlo[nxt * 2112 + ch * 132 + hown] = hl;
        if (ch < nact)
          h1o[((size_t)(base + ch) * TL + tt) * 256 + dir * 128 + hown] = hh;
      }
      barrier_lgkm();
    }

  } else if (bid < nL1 + nL2){
    // ================= L2: H=64; proj (K=256) via MFMA lookahead. ==========
    const int i2 = bid - nL1;
    const int bloc = i2 >> 1, dir = i2 & 1;
    const unsigned short* h1i = (p2 ? h1r1 : h1r0) + (size_t)bloc * TL * 256;
    unsigned short* o2o = p2 ? o2r1 : o2r0;
    const int kc = tid & 7, u = tid >> 3;

    float4 wr[4][2]; float bs[4];
    const float* WR = Whh2 + dir * 16384;
    #pragma unroll
    for (int tgt = 0; tgt < 4; ++tgt){
      const int row = tgt * 64 + u;
      wr[tgt][0] = *(const float4*)(WR + row * 64 + kc * 8);
      wr[tgt][1] = *(const float4*)(WR + row * 64 + kc * 8 + 4);
      bs[tgt] = bih2[dir * 256 + row] + bhh2[dir * 256 + row];
    }
    bfx8 Bf[2][8];
    const float* WP = Wih2 + dir * 65536;
    #pragma unroll
    for (int ntl = 0; ntl < 2; ++ntl){
      const int n = (2 * wv + ntl) * 16 + (lane & 15);
      #pragma unroll
      for (int Kf = 0; Kf < 8; ++Kf)
        Bf[ntl][Kf] = pack8(WP + n * 256 + Kf * 32 + (lane >> 4) * 8);
    }
    float* xs  = (float*)smem;                   // 2 bufs x 16 x 258 f
    float* h2b = (float*)(smem + 33024);         // 2 x 64 f
    if (tid < 64){ h2b[tid] = 0.0f; h2b[64 + tid] = 0.0f; }

    auto loadA = [&](int blk, uint4* a8){
      const int mm  = lane & 15;
      const int pt = dir ? (TL - 1 - (blk * 16 + mm)) : (blk * 16 + mm);
      const unsigned short* bptr = h1i + (size_t)pt * 256 + (lane >> 4) * 8;
      #pragma unroll
      for (int Kf = 0; Kf < 8; ++Kf) a8[Kf] = *(const uint4*)(bptr + Kf * 32);
    };
    auto domfma = [&](uint4* a8, int buf){
      fx4 acc0 = {0.f,0.f,0.f,0.f}, acc1 = {0.f,0.f,0.f,0.f};
      #pragma unroll
      for (int Kf = 0; Kf < 8; ++Kf){
        bfx8 av; __builtin_memcpy(&av, &a8[Kf], 16);
        acc0 = __builtin_amdgcn_mfma_f32_16x16x32_bf16(av, Bf[0][Kf], acc0, 0, 0, 0);
        acc1 = __builtin_amdgcn_mfma_f32_16x16x32_bf16(av, Bf[1][Kf], acc1, 0, 0, 0);
      }
      const int c0 = (2 * wv) * 16 + (lane & 15);
      #pragma unroll
      for (int rr = 0; rr < 4; ++rr){
        const int row = (lane >> 4) * 4 + rr;
        xs[buf * 4128 + row * 258 + c0]      = acc0[rr];
        xs[buf * 4128 + row * 258 + c0 + 16] = acc1[rr];
      }
    };

    uint4 a8[8];
    loadA(0, a8); domfma(a8, 0);
    loadA(1, a8); domfma(a8, 1);
    __syncthreads();

    float cst = 0.0f;
    uint4 pf[8];
    for (int B = 0; B < 128; ++B){
      if (B + 2 < 128) loadA(B + 2, pf);
      const int pb = B & 1;
      for (int s = 0; s < 16; ++s){
        const int t  = B * 16 + s;
        const int tt = dir ? (TL - 1 - t) : t;
        const int cur = t & 1;
        const float4* hv4 = (const float4*)(h2b + cur * 64) + kc * 2;
        const float4 hA = hv4[0], hB = hv4[1];
        float a0 = dot4(wr[0][1], hB, dot4(wr[0][0], hA, 0.f));
        float a1 = dot4(wr[1][1], hB, dot4(wr[1][0], hA, 0.f));
        float a2 = dot4(wr[2][1], hB, dot4(wr[2][0], hA, 0.f));
        float a3 = dot4(wr[3][1], hB, dot4(wr[3][0], hA, 0.f));
        a0 = swz4_add(dpp_xadd<0x4E>(dpp_xadd<0xB1>(a0)));
        a1 = swz4_add(dpp_xadd<0x4E>(dpp_xadd<0xB1>(a1)));
        a2 = swz4_add(dpp_xadd<0x4E>(dpp_xadd<0xB1>(a2)));
        a3 = swz4_add(dpp_xadd<0x4E>(dpp_xadd<0xB1>(a3)));
        if (kc == 0){
          const float* xr = xs + pb * 4128 + s * 258 + u;
          const float ig = sigf(a0 + xr[0]   + bs[0]);
          const float fg = sigf(a1 + xr[64]  + bs[1]);
          const float gg = tanhff(a2 + xr[128] + bs[2]);
          const float og = sigf(a3 + xr[192] + bs[3]);
          cst = fmaf(fg, cst, ig * gg);
          const float h = og * tanhff(cst);
          h2b[(cur ^ 1) * 64 + u] = h;
          o2o[((size_t)bloc * TL + tt) * 128 + dir * 64 + u] = f2bf(h);
        }
        barrier_lgkm();
      }
      if (B + 2 < 128) domfma(pf, pb);
    }

  } else {
    // ================= L3: H=16; proj (K=128) via MFMA; T-mean in regs. ====
    // WG = 4 chains (same dir); chunk sizes must be multiples of 4.
    const int i3 = bid - nL1 - nL2;
    const int dir = i3 & 1, q4 = i3 >> 1;
    const int grp = tid >> 7, lt = tid & 127;
    const int bloc = q4 * 4 + grp;
    const unsigned short* o2i = (p3 ? o2r1 : o2r0) + (size_t)bloc * TL * 128;
    const int u = lt >> 3, j = lt & 7, gt = j >> 1, kc = j & 1;
    const int half = wv & 1;

    const float* WR = Whh3 + dir * 1024;
    const int r = gt * 16 + u;
    const float4 wr0 = *(const float4*)(WR + r * 16 + kc * 8);
    const float4 wr1 = *(const float4*)(WR + r * 16 + kc * 8 + 4);
    const float bsv = bih3[dir * 64 + r] + bhh3[dir * 64 + r];
    const int ubase = lane & ~7;
    const float bI = bperm(bsv, ubase + 0), bF = bperm(bsv, ubase + 2);
    const float bG = bperm(bsv, ubase + 4), bO = bperm(bsv, ubase + 6);

    bfx8 Bf[2][4];
    const float* WP = Wih3 + dir * 8192;     // (64,128)
    #pragma unroll
    for (int ntl = 0; ntl < 2; ++ntl){
      const int n = (2 * half + ntl) * 16 + (lane & 15);
      #pragma unroll
      for (int Kf = 0; Kf < 4; ++Kf)
        Bf[ntl][Kf] = pack8(WP + n * 128 + Kf * 32 + (lane >> 4) * 8);
    }
    float* xs  = (float*)smem + grp * 2112;  // per chain: 2 bufs x 16 x 66 f
    float* h3b = (float*)(smem + 33792) + grp * 32;
    if (lt < 32) h3b[lt] = 0.0f;

    auto loadA3 = [&](int blk, uint4* a4){
      const int mm  = lane & 15;
      const int pt = dir ? (TL - 1 - (blk * 16 + mm)) : (blk * 16 + mm);
      const unsigned short* bptr = o2i + (size_t)pt * 128 + (lane >> 4) * 8;
      #pragma unroll
      for (int Kf = 0; Kf < 4; ++Kf) a4[Kf] = *(const uint4*)(bptr + Kf * 32);
    };
    auto domfma3 = [&](uint4* a4, int buf){
      fx4 acc0 = {0.f,0.f,0.f,0.f}, acc1 = {0.f,0.f,0.f,0.f};
      #pragma unroll
      for (int Kf = 0; Kf < 4; ++Kf){
        bfx8 av; __builtin_memcpy(&av, &a4[Kf], 16);
        acc0 = __builtin_amdgcn_mfma_f32_16x16x32_bf16(av, Bf[0][Kf], acc0, 0, 0, 0);
        acc1 = __builtin_amdgcn_mfma_f32_16x16x32_bf16(av, Bf[1][Kf], acc1, 0, 0, 0);
      }
      const int c0 = (2 * half) * 16 + (lane & 15);
      #pragma unroll
      for (int rr = 0; rr < 4; ++rr){
        const int row = (lane >> 4) * 4 + rr;
        xs[buf * 1056 + row * 66 + c0]      = acc0[rr];
        xs[buf * 1056 + row * 66 + c0 + 16] = acc1[rr];
      }
    };

    uint4 a4[4];
    loadA3(0, a4); domfma3(a4, 0);
    loadA3(1, a4); domfma3(a4, 1);
    __syncthreads();

    float cst = 0.0f, msum = 0.0f;
    uint4 pf[4];
    for (int B = 0; B < 128; ++B){
      if (B + 2 < 128) loadA3(B + 2, pf);
      const int pb = B & 1;
      for (int s = 0; s < 16; ++s){
        const int t = B * 16 + s;
        const int cur = t & 1;
        const float4* h3p = (const float4*)(h3b + cur * 16 + kc * 8);
        float acc = dot4(wr1, h3p[1], dot4(wr0, h3p[0], 0.f));
        acc = dpp_xadd<0xB1>(acc);
        const float gI = bperm(acc, ubase + 0), gF = bperm(acc, ubase + 2);
        const float gG = bperm(acc, ubase + 4), gO = bperm(acc, ubase + 6);
        if (j == 0){
          const float* xr = xs + pb * 1056 + s * 66 + u;
          const float ig = sigf(gI + bI + xr[0]);
          const float fg = sigf(gF + bF + xr[16]);
          const float gg = tanhff(gG + bG + xr[32]);
          const float og = sigf(gO + bO + xr[48]);
          cst = fmaf(fg, cst, ig * gg);
          const float h = og * tanhff(cst);
          h3b[(cur ^ 1) * 16 + u] = h;
          msum += h;
        }
        barrier_lgkm();
      }
      if (B + 2 < 128) domfma3(pf, pb);
    }
    if (j == 0) sums[(size_t)(cb3 + bloc) * 32 + dir * 16 + u] = msum;
  }
}

// ---------------- head: mean (pre-summed) + MLP, one 64-thr WG per batch
__global__ __launch_bounds__(64) void head_kernel(
    const float* __restrict__ sums,
    const float* __restrict__ hW1, const float* __restrict__ hb1,
    const float* __restrict__ hW2, const float* __restrict__ hb2,
    const float* __restrict__ hW3, const float* __restrict__ hb3,
    float* __restrict__ out)
{
  __shared__ float m[32], h1s[64], h2s[16];
  const int tid = threadIdx.x, b = blockIdx.x;
  if (tid < 32) m[tid] = sums[b * 32 + tid] * (1.0f / 2048.0f);
  __syncthreads();
  {
    float a = hb1[tid];
    #pragma unroll
    for (int k = 0; k < 32; ++k) a = fmaf(m[k], hW1[tid * 32 + k], a);
    h1s[tid] = fmaxf(a, 0.0f);
  }
  __syncthreads();
  if (tid < 16){
    float a = hb2[tid];
    #pragma unroll
    for (int k = 0; k < 64; ++k) a = fmaf(h1s[k], hW2[tid * 64 + k], a);
    h2s[tid] = fmaxf(a, 0.0f);
  }
  __syncthreads();
  if (tid < 20){
    float a = hb3[tid];
    #pragma unroll
    for (int k = 0; k < 16; ++k) a = fmaf(h2s[k], hW3[tid * 16 + k], a);
    out[b * 20 + tid] = a;
  }
}

extern "C" void kernel_launch(void* const* d_in, const int* in_sizes, int n_in,
                              void* d_out, int out_size, void* d_ws, size_t ws_size,
                              hipStream_t stream) {
  (void)in_sizes; (void)n_in; (void)out_size;
  const float* x    = (const float*)d_in[0];
  const float* Wih1 = (const float*)d_in[1];
  const float* Whh1 = (const float*)d_in[2];
  const float* bih1 = (const float*)d_in[3];
  const float* bhh1 = (const float*)d_in[4];
  const float* Wih2 = (const float*)d_in[5];
  const float* Whh2 = (const float*)d_in[6];
  const float* bih2 = (const float*)d_in[7];
  const float* bhh2 = (const float*)d_in[8];
  const float* Wih3 = (const float*)d_in[9];
  const float* Whh3 = (const float*)d_in[10];
  const float* bih3 = (const float*)d_in[11];
  const float* bhh3 = (const float*)d_in[12];
  const float* hW1  = (const float*)d_in[13];
  const float* hb1  = (const float*)d_in[14];
  const float* hW2  = (const float*)d_in[15];
  const float* hb2  = (const float*)d_in[16];
  const float* hW3  = (const float*)d_in[17];
  const float* hb3  = (const float*)d_in[18];
  unsigned char* ws = (unsigned char*)d_ws;

  if (ws_size >= 402685952ull) {
    // ===== Tier 1: fully serialized, full-width stages. =====
    unsigned short* h1 = (unsigned short*)ws;
    unsigned short* o2 = (unsigned short*)(ws + 268435456u);
    float* sums = (float*)(ws + 402653184u);
    mega_kernel<<<dim3(32), dim3(512), 0, stream>>>(    // L1: 512 chains/16
        32, 0, 0, 0, 0, 0, 256, 0, 0, 0,
        x, Wih1, Whh1, bih1, bhh1, Wih2, Whh2, bih2, bhh2,
        Wih3, Whh3, bih3, bhh3, h1, h1, o2, o2, sums);
    mega_kernel<<<dim3(512), dim3(512), 0, stream>>>(   // L2
        0, 512, 0, 0, 0, 0, 0, 0, 0, 0,
        x, Wih1, Whh1, bih1, bhh1, Wih2, Whh2, bih2, bhh2,
        Wih3, Whh3, bih3, bhh3, h1, h1, o2, o2, sums);
    mega_kernel<<<dim3(128), dim3(512), 0, stream>>>(   // L3
        0, 0, 128, 0, 0, 0, 0, 0, 0, 0,
        x, Wih1, Whh1, bih1, bhh1, Wih2, Whh2, bih2, bhh2,
        Wih3, Whh3, bih3, bhh3, h1, h1, o2, o2, sums);
    head_kernel<<<dim3(256), dim3(64), 0, stream>>>(
        sums, hW1, hb1, hW2, hb2, hW3, hb3, (float*)d_out);
    return;
  }

  // ===== Ring pipeline, capacity graded by ws_size (known bracket:
  // [276.9 MB, 335.6 MB) -> C=88 branch). Footprint(C) = C*3,145,728 +
  // 32,768 B. L1 batched: nL1 = 2*ceil(chunk/16); every grid <=256 blocks
  // -> 1 block/CU everywhere, no oversubscription.
  {
    int cs[5]; int nch; size_t C;
    if (ws_size >= 276856832ull)      { C = 88; nch = 3; cs[0] = 88; cs[1] = 84; cs[2] = 84; }
    else if (ws_size >= 201359360ull) { C = 64; nch = 4; cs[0] = cs[1] = cs[2] = cs[3] = 64; }
    else                              { C = 52; nch = 5; cs[0] = cs[1] = cs[2] = cs[3] = 52; cs[4] = 48; }

    unsigned short* h1r0 = (unsigned short*)ws;
    unsigned short* h1r1 = h1r0 + C * (size_t)TL * 256;
    unsigned short* o2r0 = (unsigned short*)(ws + C * 2097152ull);
    unsigned short* o2r1 = o2r0 + C * (size_t)TL * 128;
    float* sums = (float*)(ws + C * 3145728ull);

    int co[5]; co[0] = 0;
    for (int i = 1; i < nch; ++i) co[i] = co[i - 1] + cs[i - 1];

    for (int k = 0; k < nch + 2; ++k){
      const int a1 = (k < nch) ? cs[k] : 0;
      const int a2 = (k >= 1 && k < nch + 1) ? cs[k - 1] : 0;
      const int a3 = (k >= 2) ? cs[k - 2] : 0;
      const int nL1 = a1 ? 2 * ((a1 + 15) / 16) : 0;
      const int nL2 = 2 * a2, nL3 = a3 / 2;
      mega_kernel<<<dim3(nL1 + nL2 + nL3), dim3(512), 0, stream>>>(
          nL1, nL2, nL3,
          (k < nch) ? co[k] : 0, (k >= 1 && k < nch + 1) ? co[k - 1] : 0,
          (k >= 2) ? co[k - 2] : 0, a1,
          k & 1, (k + 1) & 1, k & 1,
          x, Wih1, Whh1, bih1, bhh1, Wih2, Whh2, bih2, bhh2,
          Wih3, Whh3, bih3, bhh3, h1r0, h1r1, o2r0, o2r1, sums);
    }
    head_kernel<<<dim3(256), dim3(64), 0, stream>>>(
        sums, hW1, hb1, hW2, hb2, hW3, hb3, (float*)d_out);
  }
}

// Round 7
// 8570.393 us; speedup vs baseline: 2.7827x; 2.7827x over previous
//
#include <hip/hip_runtime.h>

#define TL 2048

typedef __attribute__((ext_vector_type(8))) short bfx8;
typedef __attribute__((ext_vector_type(4))) float fx4;
typedef __attribute__((ext_vector_type(2))) float fx2;

__device__ __forceinline__ float sigf(float x){ return __builtin_amdgcn_rcpf(1.0f + __expf(-x)); }
__device__ __forceinline__ float tanhff(float x){ return fmaf(2.0f, sigf(2.0f*x), -1.0f); }

template<int CTRL>
__device__ __forceinline__ float dpp_xadd(float v){
  int s = __builtin_amdgcn_update_dpp(0, __float_as_int(v), CTRL, 0xF, 0xF, true);
  return v + __int_as_float(s);
}
__device__ __forceinline__ float swz4_add(float v){
  int s = __builtin_amdgcn_ds_swizzle(__float_as_int(v), 0x101F);
  return v + __int_as_float(s);
}
__device__ __forceinline__ float bperm(float v, int srclane){
  return __int_as_float(__builtin_amdgcn_ds_bpermute(srclane << 2, __float_as_int(v)));
}
__device__ __forceinline__ unsigned short f2bf(float f){   // RNE fp32->bf16
  unsigned int u = __float_as_uint(f);
  u += 0x7fffu + ((u >> 16) & 1u);
  return (unsigned short)(u >> 16);
}
__device__ __forceinline__ float dot4(float4 a, float4 b, float acc){
  acc = fmaf(a.x, b.x, acc); acc = fmaf(a.y, b.y, acc);
  acc = fmaf(a.z, b.z, acc); acc = fmaf(a.w, b.w, acc);
  return acc;
}
// LDS-only barrier: do NOT drain vmcnt (global h-stores stay in flight).
__device__ __forceinline__ void barrier_lgkm(){
  asm volatile("s_waitcnt lgkmcnt(0)\ns_barrier" ::: "memory");
}
__device__ __forceinline__ bfx8 pack8(const float* p){
  bfx8 r;
  #pragma unroll
  for (int i = 0; i < 8; ++i) r[i] = (short)f2bf(p[i]);
  return r;
}

// Uber-kernel; segments selected per-block by [nL1 | nL2 | nL3]:
//   blockIdx [0,nL1)            : L1 scan (fp32 VALU, D=2 folded), h1 out bf16
//   blockIdx [nL1,nL1+nL2)      : L2 scan, Wih2 proj via MFMA 16-step lookahead
//   blockIdx [nL1+nL2, +nL3)    : L3 scan, Wih3 proj via MFMA + T-mean accumulate
// HISTORY (do not regress):
//  - launch_bounds must stay (512,2): (512,4) caps VGPR at 64 -> spill (r1).
//  - MFMA-batched L1 (r4-r6) is latency-bound at 1 WG/CU: 2.9-5.5 ms vs this
//    VALU scan's 1.4 ms. Reverted.
//  - r7 change: L1 inner dot uses <2 x float> accumulation so clang emits
//    v_pk_fma_f32 (2 fp32 FMA / inst, gfx90a+): 128 fma -> 64 pk per step.
__global__ __launch_bounds__(512, 2) void mega_kernel(
    int nL1, int nL2, int nL3, int cb1, int cb2, int cb3, int p1, int p2, int p3,
    const float* __restrict__ x,
    const float* __restrict__ Wih1, const float* __restrict__ Whh1,
    const float* __restrict__ bih1, const float* __restrict__ bhh1,
    const float* __restrict__ Wih2, const float* __restrict__ Whh2,
    const float* __restrict__ bih2, const float* __restrict__ bhh2,
    const float* __restrict__ Wih3, const float* __restrict__ Whh3,
    const float* __restrict__ bih3, const float* __restrict__ bhh3,
    unsigned short* __restrict__ h1r0, unsigned short* __restrict__ h1r1,
    unsigned short* __restrict__ o2r0, unsigned short* __restrict__ o2r1,
    float* __restrict__ sums)
{
  __shared__ __align__(16) unsigned char smem[34816];
  const int tid  = threadIdx.x;
  const int bid  = blockIdx.x;
  const int lane = tid & 63;
  const int wv   = tid >> 6;

  if (bid < nL1){
    // ================= L1: H=128, D=2 folded. WG = one (b,dir) chain. ======
    const int bloc = bid >> 1, dir = bid & 1;
    unsigned short* h1o = p1 ? h1r1 : h1r0;
    const int kc = tid & 3, u = tid >> 2;

    // Weights as fx2 pairs (same 128 regs) for v_pk_fma_f32 accumulation.
    fx2 w2[4][16];
    const float* Wh = Whh1 + dir * 65536;
    #pragma unroll
    for (int g = 0; g < 4; ++g){
      const float* row = Wh + (g * 128 + u) * 128 + kc * 32;
      #pragma unroll
      for (int q = 0; q < 8; ++q){
        const int ro = (q + 2 * kc) & 7;
        const float4 t = *(const float4*)(row + ro * 4);
        w2[g][2 * q]     = fx2{t.x, t.y};
        w2[g][2 * q + 1] = fx2{t.z, t.w};
      }
    }
    float xwA[4], xwB[4], bs[4];
    #pragma unroll
    for (int g = 0; g < 4; ++g){
      const int r = g * 128 + u;
      xwA[g] = Wih1[dir * 1024 + r * 2];
      xwB[g] = Wih1[dir * 1024 + r * 2 + 1];
      bs[g]  = bih1[dir * 512 + r] + bhh1[dir * 512 + r];
    }
    float* xlds = (float*)smem;                  // 4096 f (full x row)
    float* hbuf = (float*)(smem + 16384);        // 2 x 128 f
    {
      const float* xb = x + (size_t)(cb1 + bloc) * (TL * 2);
      for (int idx = tid; idx < TL * 2; idx += 512) xlds[idx] = xb[idx];
    }
    if (tid < 128){ hbuf[tid] = 0.0f; hbuf[128 + tid] = 0.0f; }
    __syncthreads();

    float cst = 0.0f;
    for (int t = 0; t < TL; ++t){
      const int tt  = dir ? (TL - 1 - t) : t;
      const int cur = t & 1;
      const float4* hp = (const float4*)(hbuf + cur * 128) + kc * 8;
      fx2 s0 = {0.f,0.f}, s1 = {0.f,0.f}, s2 = {0.f,0.f}, s3 = {0.f,0.f};
      #pragma unroll
      for (int q = 0; q < 8; ++q){
        const float4 hv = hp[(q + 2 * kc) & 7];
        const fx2 hA = fx2{hv.x, hv.y}, hB = fx2{hv.z, hv.w};
        s0 += w2[0][2*q] * hA; s0 += w2[0][2*q+1] * hB;
        s1 += w2[1][2*q] * hA; s1 += w2[1][2*q+1] * hB;
        s2 += w2[2][2*q] * hA; s2 += w2[2][2*q+1] * hB;
        s3 += w2[3][2*q] * hA; s3 += w2[3][2*q+1] * hB;
      }
      float a0 = s0.x + s0.y, a1 = s1.x + s1.y;
      float a2 = s2.x + s2.y, a3 = s3.x + s3.y;
      a0 = dpp_xadd<0x4E>(dpp_xadd<0xB1>(a0));
      a1 = dpp_xadd<0x4E>(dpp_xadd<0xB1>(a1));
      a2 = dpp_xadd<0x4E>(dpp_xadd<0xB1>(a2));
      a3 = dpp_xadd<0x4E>(dpp_xadd<0xB1>(a3));
      if (kc == 0){
        const float x0 = xlds[tt * 2], x1 = xlds[tt * 2 + 1];
        const float p0 = a0 + fmaf(xwA[0], x0, fmaf(xwB[0], x1, bs[0]));
        const float p1 = a1 + fmaf(xwA[1], x0, fmaf(xwB[1], x1, bs[1]));
        const float p2 = a2 + fmaf(xwA[2], x0, fmaf(xwB[2], x1, bs[2]));
        const float p3 = a3 + fmaf(xwA[3], x0, fmaf(xwB[3], x1, bs[3]));
        const float ig = sigf(p0), fg = sigf(p1), gg = tanhff(p2), og = sigf(p3);
        cst = fmaf(fg, cst, ig * gg);
        const float h = og * tanhff(cst);
        hbuf[(cur ^ 1) * 128 + u] = h;
        h1o[((size_t)bloc * TL + tt) * 256 + dir * 128 + u] = f2bf(h);
      }
      barrier_lgkm();
    }

  } else if (bid < nL1 + nL2){
    // ================= L2: H=64; proj (K=256) via MFMA lookahead. ==========
    const int i2 = bid - nL1;
    const int bloc = i2 >> 1, dir = i2 & 1;
    const unsigned short* h1i = (p2 ? h1r1 : h1r0) + (size_t)bloc * TL * 256;
    unsigned short* o2o = p2 ? o2r1 : o2r0;
    const int kc = tid & 7, u = tid >> 3;

    float4 wr[4][2]; float bs[4];
    const float* WR = Whh2 + dir * 16384;
    #pragma unroll
    for (int tgt = 0; tgt < 4; ++tgt){
      const int row = tgt * 64 + u;
      wr[tgt][0] = *(const float4*)(WR + row * 64 + kc * 8);
      wr[tgt][1] = *(const float4*)(WR + row * 64 + kc * 8 + 4);
      bs[tgt] = bih2[dir * 256 + row] + bhh2[dir * 256 + row];
    }
    bfx8 Bf[2][8];
    const float* WP = Wih2 + dir * 65536;
    #pragma unroll
    for (int ntl = 0; ntl < 2; ++ntl){
      const int n = (2 * wv + ntl) * 16 + (lane & 15);
      #pragma unroll
      for (int Kf = 0; Kf < 8; ++Kf)
        Bf[ntl][Kf] = pack8(WP + n * 256 + Kf * 32 + (lane >> 4) * 8);
    }
    float* xs  = (float*)smem;                   // 2 bufs x 16 x 258 f
    float* h2b = (float*)(smem + 33024);         // 2 x 64 f
    if (tid < 64){ h2b[tid] = 0.0f; h2b[64 + tid] = 0.0f; }

    auto loadA = [&](int blk, uint4* a8){
      const int m  = lane & 15;
      const int pt = dir ? (TL - 1 - (blk * 16 + m)) : (blk * 16 + m);
      const unsigned short* base = h1i + (size_t)pt * 256 + (lane >> 4) * 8;
      #pragma unroll
      for (int Kf = 0; Kf < 8; ++Kf) a8[Kf] = *(const uint4*)(base + Kf * 32);
    };
    auto domfma = [&](uint4* a8, int buf){
      fx4 acc0 = {0.f,0.f,0.f,0.f}, acc1 = {0.f,0.f,0.f,0.f};
      #pragma unroll
      for (int Kf = 0; Kf < 8; ++Kf){
        bfx8 av; __builtin_memcpy(&av, &a8[Kf], 16);
        acc0 = __builtin_amdgcn_mfma_f32_16x16x32_bf16(av, Bf[0][Kf], acc0, 0, 0, 0);
        acc1 = __builtin_amdgcn_mfma_f32_16x16x32_bf16(av, Bf[1][Kf], acc1, 0, 0, 0);
      }
      const int c0 = (2 * wv) * 16 + (lane & 15);
      #pragma unroll
      for (int rr = 0; rr < 4; ++rr){
        const int row = (lane >> 4) * 4 + rr;
        xs[buf * 4128 + row * 258 + c0]      = acc0[rr];
        xs[buf * 4128 + row * 258 + c0 + 16] = acc1[rr];
      }
    };

    uint4 a8[8];
    loadA(0, a8); domfma(a8, 0);
    loadA(1, a8); domfma(a8, 1);
    __syncthreads();

    float cst = 0.0f;
    uint4 pf[8];
    for (int B = 0; B < 128; ++B){
      if (B + 2 < 128) loadA(B + 2, pf);      // issue; consumed after the 16 steps
      const int pb = B & 1;
      for (int s = 0; s < 16; ++s){
        const int t  = B * 16 + s;
        const int tt = dir ? (TL - 1 - t) : t;
        const int cur = t & 1;
        const float4* hv4 = (const float4*)(h2b + cur * 64) + kc * 2;
        const float4 hA = hv4[0], hB = hv4[1];
        float a0 = dot4(wr[0][1], hB, dot4(wr[0][0], hA, 0.f));
        float a1 = dot4(wr[1][1], hB, dot4(wr[1][0], hA, 0.f));
        float a2 = dot4(wr[2][1], hB, dot4(wr[2][0], hA, 0.f));
        float a3 = dot4(wr[3][1], hB, dot4(wr[3][0], hA, 0.f));
        a0 = swz4_add(dpp_xadd<0x4E>(dpp_xadd<0xB1>(a0)));
        a1 = swz4_add(dpp_xadd<0x4E>(dpp_xadd<0xB1>(a1)));
        a2 = swz4_add(dpp_xadd<0x4E>(dpp_xadd<0xB1>(a2)));
        a3 = swz4_add(dpp_xadd<0x4E>(dpp_xadd<0xB1>(a3)));
        if (kc == 0){
          const float* xr = xs + pb * 4128 + s * 258 + u;
          const float ig = sigf(a0 + xr[0]   + bs[0]);
          const float fg = sigf(a1 + xr[64]  + bs[1]);
          const float gg = tanhff(a2 + xr[128] + bs[2]);
          const float og = sigf(a3 + xr[192] + bs[3]);
          cst = fmaf(fg, cst, ig * gg);
          const float h = og * tanhff(cst);
          h2b[(cur ^ 1) * 64 + u] = h;
          o2o[((size_t)bloc * TL + tt) * 128 + dir * 64 + u] = f2bf(h);
        }
        barrier_lgkm();
      }
      if (B + 2 < 128) domfma(pf, pb);        // fills buf pb for block B+2
    }

  } else {
    // ================= L3: H=16; proj (K=128) via MFMA; T-mean in regs. ====
    // WG = 4 chains (same dir); chunk sizes must be multiples of 4.
    const int i3 = bid - nL1 - nL2;
    const int dir = i3 & 1, q4 = i3 >> 1;
    const int grp = tid >> 7, lt = tid & 127;
    const int bloc = q4 * 4 + grp;
    const unsigned short* o2i = (p3 ? o2r1 : o2r0) + (size_t)bloc * TL * 128;
    const int u = lt >> 3, j = lt & 7, gt = j >> 1, kc = j & 1;
    const int half = wv & 1;

    const float* WR = Whh3 + dir * 1024;
    const int r = gt * 16 + u;
    const float4 wr0 = *(const float4*)(WR + r * 16 + kc * 8);
    const float4 wr1 = *(const float4*)(WR + r * 16 + kc * 8 + 4);
    const float bsv = bih3[dir * 64 + r] + bhh3[dir * 64 + r];
    const int ubase = lane & ~7;
    const float bI = bperm(bsv, ubase + 0), bF = bperm(bsv, ubase + 2);
    const float bG = bperm(bsv, ubase + 4), bO = bperm(bsv, ubase + 6);

    bfx8 Bf[2][4];
    const float* WP = Wih3 + dir * 8192;     // (64,128)
    #pragma unroll
    for (int ntl = 0; ntl < 2; ++ntl){
      const int n = (2 * half + ntl) * 16 + (lane & 15);
      #pragma unroll
      for (int Kf = 0; Kf < 4; ++Kf)
        Bf[ntl][Kf] = pack8(WP + n * 128 + Kf * 32 + (lane >> 4) * 8);
    }
    float* xs  = (float*)smem + grp * 2112;  // per chain: 2 bufs x 16 x 66 f
    float* h3b = (float*)(smem + 33792) + grp * 32;
    if (lt < 32) h3b[lt] = 0.0f;

    auto loadA3 = [&](int blk, uint4* a4){
      const int m  = lane & 15;
      const int pt = dir ? (TL - 1 - (blk * 16 + m)) : (blk * 16 + m);
      const unsigned short* base = o2i + (size_t)pt * 128 + (lane >> 4) * 8;
      #pragma unroll
      for (int Kf = 0; Kf < 4; ++Kf) a4[Kf] = *(const uint4*)(base + Kf * 32);
    };
    auto domfma3 = [&](uint4* a4, int buf){
      fx4 acc0 = {0.f,0.f,0.f,0.f}, acc1 = {0.f,0.f,0.f,0.f};
      #pragma unroll
      for (int Kf = 0; Kf < 4; ++Kf){
        bfx8 av; __builtin_memcpy(&av, &a4[Kf], 16);
        acc0 = __builtin_amdgcn_mfma_f32_16x16x32_bf16(av, Bf[0][Kf], acc0, 0, 0, 0);
        acc1 = __builtin_amdgcn_mfma_f32_16x16x32_bf16(av, Bf[1][Kf], acc1, 0, 0, 0);
      }
      const int c0 = (2 * half) * 16 + (lane & 15);
      #pragma unroll
      for (int rr = 0; rr < 4; ++rr){
        const int row = (lane >> 4) * 4 + rr;
        xs[buf * 1056 + row * 66 + c0]      = acc0[rr];
        xs[buf * 1056 + row * 66 + c0 + 16] = acc1[rr];
      }
    };

    uint4 a4[4];
    loadA3(0, a4); domfma3(a4, 0);
    loadA3(1, a4); domfma3(a4, 1);
    __syncthreads();

    float cst = 0.0f, msum = 0.0f;
    uint4 pf[4];
    for (int B = 0; B < 128; ++B){
      if (B + 2 < 128) loadA3(B + 2, pf);
      const int pb = B & 1;
      for (int s = 0; s < 16; ++s){
        const int t = B * 16 + s;
        const int cur = t & 1;
        const float4* h3p = (const float4*)(h3b + cur * 16 + kc * 8);
        float acc = dot4(wr1, h3p[1], dot4(wr0, h3p[0], 0.f));
        acc = dpp_xadd<0xB1>(acc);
        const float gI = bperm(acc, ubase + 0), gF = bperm(acc, ubase + 2);
        const float gG = bperm(acc, ubase + 4), gO = bperm(acc, ubase + 6);
        if (j == 0){
          const float* xr = xs + pb * 1056 + s * 66 + u;
          const float ig = sigf(gI + bI + xr[0]);
          const float fg = sigf(gF + bF + xr[16]);
          const float gg = tanhff(gG + bG + xr[32]);
          const float og = sigf(gO + bO + xr[48]);
          cst = fmaf(fg, cst, ig * gg);
          const float h = og * tanhff(cst);
          h3b[(cur ^ 1) * 16 + u] = h;
          msum += h;
        }
        barrier_lgkm();
      }
      if (B + 2 < 128) domfma3(pf, pb);
    }
    if (j == 0) sums[(size_t)(cb3 + bloc) * 32 + dir * 16 + u] = msum;
  }
}

// ---------------- head: mean (pre-summed) + MLP, one 64-thr WG per batch
__global__ __launch_bounds__(64) void head_kernel(
    const float* __restrict__ sums,
    const float* __restrict__ hW1, const float* __restrict__ hb1,
    const float* __restrict__ hW2, const float* __restrict__ hb2,
    const float* __restrict__ hW3, const float* __restrict__ hb3,
    float* __restrict__ out)
{
  __shared__ float m[32], h1s[64], h2s[16];
  const int tid = threadIdx.x, b = blockIdx.x;
  if (tid < 32) m[tid] = sums[b * 32 + tid] * (1.0f / 2048.0f);
  __syncthreads();
  {
    float a = hb1[tid];
    #pragma unroll
    for (int k = 0; k < 32; ++k) a = fmaf(m[k], hW1[tid * 32 + k], a);
    h1s[tid] = fmaxf(a, 0.0f);
  }
  __syncthreads();
  if (tid < 16){
    float a = hb2[tid];
    #pragma unroll
    for (int k = 0; k < 64; ++k) a = fmaf(h1s[k], hW2[tid * 64 + k], a);
    h2s[tid] = fmaxf(a, 0.0f);
  }
  __syncthreads();
  if (tid < 20){
    float a = hb3[tid];
    #pragma unroll
    for (int k = 0; k < 16; ++k) a = fmaf(h2s[k], hW3[tid * 16 + k], a);
    out[b * 20 + tid] = a;
  }
}

extern "C" void kernel_launch(void* const* d_in, const int* in_sizes, int n_in,
                              void* d_out, int out_size, void* d_ws, size_t ws_size,
                              hipStream_t stream) {
  (void)in_sizes; (void)n_in; (void)out_size;
  const float* x    = (const float*)d_in[0];
  const float* Wih1 = (const float*)d_in[1];
  const float* Whh1 = (const float*)d_in[2];
  const float* bih1 = (const float*)d_in[3];
  const float* bhh1 = (const float*)d_in[4];
  const float* Wih2 = (const float*)d_in[5];
  const float* Whh2 = (const float*)d_in[6];
  const float* bih2 = (const float*)d_in[7];
  const float* bhh2 = (const float*)d_in[8];
  const float* Wih3 = (const float*)d_in[9];
  const float* Whh3 = (const float*)d_in[10];
  const float* bih3 = (const float*)d_in[11];
  const float* bhh3 = (const float*)d_in[12];
  const float* hW1  = (const float*)d_in[13];
  const float* hb1  = (const float*)d_in[14];
  const float* hW2  = (const float*)d_in[15];
  const float* hb2  = (const float*)d_in[16];
  const float* hW3  = (const float*)d_in[17];
  const float* hb3  = (const float*)d_in[18];
  unsigned char* ws = (unsigned char*)d_ws;

  if (ws_size >= 402685952ull) {
    // ===== Tier 1: fully serialized, full-width stages. =====
    unsigned short* h1 = (unsigned short*)ws;
    unsigned short* o2 = (unsigned short*)(ws + 268435456u);
    float* sums = (float*)(ws + 402653184u);
    mega_kernel<<<dim3(512), dim3(512), 0, stream>>>(   // L1: all 512 chains
        512, 0, 0, 0, 0, 0, 0, 0, 0,
        x, Wih1, Whh1, bih1, bhh1, Wih2, Whh2, bih2, bhh2,
        Wih3, Whh3, bih3, bhh3, h1, h1, o2, o2, sums);
    mega_kernel<<<dim3(512), dim3(512), 0, stream>>>(   // L2
        0, 512, 0, 0, 0, 0, 0, 0, 0,
        x, Wih1, Whh1, bih1, bhh1, Wih2, Whh2, bih2, bhh2,
        Wih3, Whh3, bih3, bhh3, h1, h1, o2, o2, sums);
    mega_kernel<<<dim3(128), dim3(512), 0, stream>>>(   // L3
        0, 0, 128, 0, 0, 0, 0, 0, 0,
        x, Wih1, Whh1, bih1, bhh1, Wih2, Whh2, bih2, bhh2,
        Wih3, Whh3, bih3, bhh3, h1, h1, o2, o2, sums);
    head_kernel<<<dim3(256), dim3(64), 0, stream>>>(
        sums, hW1, hb1, hW2, hb2, hW3, hb3, (float*)d_out);
    return;
  }

  // ===== Ring pipeline, capacity graded by ws_size (known bracket:
  // [276.9 MB, 335.6 MB) -> C=88 branch runs). Footprint(C) =
  // C*3,145,728 + 32,768 B. This is the round-3 proven schedule.
  {
    int cs[5]; int nch; size_t C;
    if (ws_size >= 276856832ull)      { C = 88; nch = 3; cs[0] = 88; cs[1] = 84; cs[2] = 84; }
    else if (ws_size >= 201359360ull) { C = 64; nch = 4; cs[0] = cs[1] = cs[2] = cs[3] = 64; }
    else                              { C = 52; nch = 5; cs[0] = cs[1] = cs[2] = cs[3] = 52; cs[4] = 48; }

    unsigned short* h1r0 = (unsigned short*)ws;
    unsigned short* h1r1 = h1r0 + C * (size_t)TL * 256;
    unsigned short* o2r0 = (unsigned short*)(ws + C * 2097152ull);
    unsigned short* o2r1 = o2r0 + C * (size_t)TL * 128;
    float* sums = (float*)(ws + C * 3145728ull);

    int co[5]; co[0] = 0;
    for (int i = 1; i < nch; ++i) co[i] = co[i - 1] + cs[i - 1];

    for (int k = 0; k < nch + 2; ++k){
      const int a1 = (k < nch) ? cs[k] : 0;
      const int a2 = (k >= 1 && k < nch + 1) ? cs[k - 1] : 0;
      const int a3 = (k >= 2) ? cs[k - 2] : 0;
      const int nL1 = 2 * a1, nL2 = 2 * a2, nL3 = a3 / 2;
      mega_kernel<<<dim3(nL1 + nL2 + nL3), dim3(512), 0, stream>>>(
          nL1, nL2, nL3,
          (k < nch) ? co[k] : 0, (k >= 1 && k < nch + 1) ? co[k - 1] : 0,
          (k >= 2) ? co[k - 2] : 0,
          k & 1, (k + 1) & 1, k & 1,
          x, Wih1, Whh1, bih1, bhh1, Wih2, Whh2, bih2, bhh2,
          Wih3, Whh3, bih3, bhh3, h1r0, h1r1, o2r0, o2r1, sums);
    }
    head_kernel<<<dim3(256), dim3(64), 0, stream>>>(
        sums, hW1, hb1, hW2, hb2, hW3, hb3, (float*)d_out);
  }
}

// Round 8
// 7136.716 us; speedup vs baseline: 3.3417x; 1.2009x over previous
//
#include <hip/hip_runtime.h>

#define TL 2048

typedef __attribute__((ext_vector_type(8))) short bfx8;
typedef __attribute__((ext_vector_type(4))) float fx4;
typedef __attribute__((ext_vector_type(2))) float fx2;

__device__ __forceinline__ float sigf(float x){ return __builtin_amdgcn_rcpf(1.0f + __expf(-x)); }
__device__ __forceinline__ float tanhff(float x){ return fmaf(2.0f, sigf(2.0f*x), -1.0f); }

template<int CTRL>
__device__ __forceinline__ float dpp_xadd(float v){
  int s = __builtin_amdgcn_update_dpp(0, __float_as_int(v), CTRL, 0xF, 0xF, true);
  return v + __int_as_float(s);
}
__device__ __forceinline__ float swz4_add(float v){
  int s = __builtin_amdgcn_ds_swizzle(__float_as_int(v), 0x101F);
  return v + __int_as_float(s);
}
__device__ __forceinline__ float bperm(float v, int srclane){
  return __int_as_float(__builtin_amdgcn_ds_bpermute(srclane << 2, __float_as_int(v)));
}
__device__ __forceinline__ unsigned short f2bf(float f){   // RNE fp32->bf16
  unsigned int u = __float_as_uint(f);
  u += 0x7fffu + ((u >> 16) & 1u);
  return (unsigned short)(u >> 16);
}
__device__ __forceinline__ float dot4(float4 a, float4 b, float acc){
  acc = fmaf(a.x, b.x, acc); acc = fmaf(a.y, b.y, acc);
  acc = fmaf(a.z, b.z, acc); acc = fmaf(a.w, b.w, acc);
  return acc;
}
// LDS-only barrier: do NOT drain vmcnt (global h-stores stay in flight).
__device__ __forceinline__ void barrier_lgkm(){
  asm volatile("s_waitcnt lgkmcnt(0)\ns_barrier" ::: "memory");
}
__device__ __forceinline__ bfx8 pack8(const float* p){
  bfx8 r;
  #pragma unroll
  for (int i = 0; i < 8; ++i) r[i] = (short)f2bf(p[i]);
  return r;
}

// Uber-kernel; segments selected per-block by [nL1 | nL2 | nL3]:
//   blockIdx [0,nL1)            : L1 scan (fp32 VALU pk_fma, D=2 folded)
//   blockIdx [nL1,nL1+nL2)      : L2 scan, Wih2 proj via MFMA lookahead
//   blockIdx [nL1+nL2, +nL3)    : L3 scan, ONE WAVE PER CHAIN (barrier-free)
// HISTORY (do not regress):
//  - launch_bounds must stay (512,2): (512,4) caps VGPR at 64 -> spill (r1).
//  - MFMA-batched L1 (r4-r6) is latency-bound at 1 WG/CU: 2.9-5.5 ms vs the
//    VALU scan's 1.4 ms. Reverted.
//  - r8: L3 was the slowest stage (~1.7 ms; 8-wave per-step s_barrier).
//    Rewritten one-wave-per-chain, barrier-free: proj accs in regs +
//    ds_bpermute spread, Wih3 bf16 in LDS (16B XOR swizzle), h3 in LDS.
__global__ __launch_bounds__(512, 2) void mega_kernel(
    int nL1, int nL2, int nL3, int cb1, int cb2, int cb3, int p1, int p2, int p3,
    const float* __restrict__ x,
    const float* __restrict__ Wih1, const float* __restrict__ Whh1,
    const float* __restrict__ bih1, const float* __restrict__ bhh1,
    const float* __restrict__ Wih2, const float* __restrict__ Whh2,
    const float* __restrict__ bih2, const float* __restrict__ bhh2,
    const float* __restrict__ Wih3, const float* __restrict__ Whh3,
    const float* __restrict__ bih3, const float* __restrict__ bhh3,
    unsigned short* __restrict__ h1r0, unsigned short* __restrict__ h1r1,
    unsigned short* __restrict__ o2r0, unsigned short* __restrict__ o2r1,
    float* __restrict__ sums)
{
  __shared__ __align__(16) unsigned char smem[34816];
  const int tid  = threadIdx.x;
  const int bid  = blockIdx.x;
  const int lane = tid & 63;
  const int wv   = tid >> 6;

  if (bid < nL1){
    // ================= L1: H=128, D=2 folded. WG = one (b,dir) chain. ======
    const int bloc = bid >> 1, dir = bid & 1;
    unsigned short* h1o = p1 ? h1r1 : h1r0;
    const int kc = tid & 3, u = tid >> 2;

    // Weights as fx2 pairs (same 128 regs) for v_pk_fma_f32 accumulation.
    fx2 w2[4][16];
    const float* Wh = Whh1 + dir * 65536;
    #pragma unroll
    for (int g = 0; g < 4; ++g){
      const float* row = Wh + (g * 128 + u) * 128 + kc * 32;
      #pragma unroll
      for (int q = 0; q < 8; ++q){
        const int ro = (q + 2 * kc) & 7;
        const float4 t = *(const float4*)(row + ro * 4);
        w2[g][2 * q]     = fx2{t.x, t.y};
        w2[g][2 * q + 1] = fx2{t.z, t.w};
      }
    }
    float xwA[4], xwB[4], bs[4];
    #pragma unroll
    for (int g = 0; g < 4; ++g){
      const int r = g * 128 + u;
      xwA[g] = Wih1[dir * 1024 + r * 2];
      xwB[g] = Wih1[dir * 1024 + r * 2 + 1];
      bs[g]  = bih1[dir * 512 + r] + bhh1[dir * 512 + r];
    }
    float* xlds = (float*)smem;                  // 4096 f (full x row)
    float* hbuf = (float*)(smem + 16384);        // 2 x 128 f
    {
      const float* xb = x + (size_t)(cb1 + bloc) * (TL * 2);
      for (int idx = tid; idx < TL * 2; idx += 512) xlds[idx] = xb[idx];
    }
    if (tid < 128){ hbuf[tid] = 0.0f; hbuf[128 + tid] = 0.0f; }
    __syncthreads();

    float cst = 0.0f;
    for (int t = 0; t < TL; ++t){
      const int tt  = dir ? (TL - 1 - t) : t;
      const int cur = t & 1;
      const float4* hp = (const float4*)(hbuf + cur * 128) + kc * 8;
      fx2 s0 = {0.f,0.f}, s1 = {0.f,0.f}, s2 = {0.f,0.f}, s3 = {0.f,0.f};
      #pragma unroll
      for (int q = 0; q < 8; ++q){
        const float4 hv = hp[(q + 2 * kc) & 7];
        const fx2 hA = fx2{hv.x, hv.y}, hB = fx2{hv.z, hv.w};
        s0 += w2[0][2*q] * hA; s0 += w2[0][2*q+1] * hB;
        s1 += w2[1][2*q] * hA; s1 += w2[1][2*q+1] * hB;
        s2 += w2[2][2*q] * hA; s2 += w2[2][2*q+1] * hB;
        s3 += w2[3][2*q] * hA; s3 += w2[3][2*q+1] * hB;
      }
      float a0 = s0.x + s0.y, a1 = s1.x + s1.y;
      float a2 = s2.x + s2.y, a3 = s3.x + s3.y;
      a0 = dpp_xadd<0x4E>(dpp_xadd<0xB1>(a0));
      a1 = dpp_xadd<0x4E>(dpp_xadd<0xB1>(a1));
      a2 = dpp_xadd<0x4E>(dpp_xadd<0xB1>(a2));
      a3 = dpp_xadd<0x4E>(dpp_xadd<0xB1>(a3));
      if (kc == 0){
        const float x0 = xlds[tt * 2], x1 = xlds[tt * 2 + 1];
        const float p0 = a0 + fmaf(xwA[0], x0, fmaf(xwB[0], x1, bs[0]));
        const float p1 = a1 + fmaf(xwA[1], x0, fmaf(xwB[1], x1, bs[1]));
        const float p2 = a2 + fmaf(xwA[2], x0, fmaf(xwB[2], x1, bs[2]));
        const float p3 = a3 + fmaf(xwA[3], x0, fmaf(xwB[3], x1, bs[3]));
        const float ig = sigf(p0), fg = sigf(p1), gg = tanhff(p2), og = sigf(p3);
        cst = fmaf(fg, cst, ig * gg);
        const float h = og * tanhff(cst);
        hbuf[(cur ^ 1) * 128 + u] = h;
        h1o[((size_t)bloc * TL + tt) * 256 + dir * 128 + u] = f2bf(h);
      }
      barrier_lgkm();
    }

  } else if (bid < nL1 + nL2){
    // ================= L2: H=64; proj (K=256) via MFMA lookahead. ==========
    const int i2 = bid - nL1;
    const int bloc = i2 >> 1, dir = i2 & 1;
    const unsigned short* h1i = (p2 ? h1r1 : h1r0) + (size_t)bloc * TL * 256;
    unsigned short* o2o = p2 ? o2r1 : o2r0;
    const int kc = tid & 7, u = tid >> 3;

    float4 wr[4][2]; float bs[4];
    const float* WR = Whh2 + dir * 16384;
    #pragma unroll
    for (int tgt = 0; tgt < 4; ++tgt){
      const int row = tgt * 64 + u;
      wr[tgt][0] = *(const float4*)(WR + row * 64 + kc * 8);
      wr[tgt][1] = *(const float4*)(WR + row * 64 + kc * 8 + 4);
      bs[tgt] = bih2[dir * 256 + row] + bhh2[dir * 256 + row];
    }
    bfx8 Bf[2][8];
    const float* WP = Wih2 + dir * 65536;
    #pragma unroll
    for (int ntl = 0; ntl < 2; ++ntl){
      const int n = (2 * wv + ntl) * 16 + (lane & 15);
      #pragma unroll
      for (int Kf = 0; Kf < 8; ++Kf)
        Bf[ntl][Kf] = pack8(WP + n * 256 + Kf * 32 + (lane >> 4) * 8);
    }
    float* xs  = (float*)smem;                   // 2 bufs x 16 x 258 f
    float* h2b = (float*)(smem + 33024);         // 2 x 64 f
    if (tid < 64){ h2b[tid] = 0.0f; h2b[64 + tid] = 0.0f; }

    auto loadA = [&](int blk, uint4* a8){
      const int m  = lane & 15;
      const int pt = dir ? (TL - 1 - (blk * 16 + m)) : (blk * 16 + m);
      const unsigned short* base = h1i + (size_t)pt * 256 + (lane >> 4) * 8;
      #pragma unroll
      for (int Kf = 0; Kf < 8; ++Kf) a8[Kf] = *(const uint4*)(base + Kf * 32);
    };
    auto domfma = [&](uint4* a8, int buf){
      fx4 acc0 = {0.f,0.f,0.f,0.f}, acc1 = {0.f,0.f,0.f,0.f};
      #pragma unroll
      for (int Kf = 0; Kf < 8; ++Kf){
        bfx8 av; __builtin_memcpy(&av, &a8[Kf], 16);
        acc0 = __builtin_amdgcn_mfma_f32_16x16x32_bf16(av, Bf[0][Kf], acc0, 0, 0, 0);
        acc1 = __builtin_amdgcn_mfma_f32_16x16x32_bf16(av, Bf[1][Kf], acc1, 0, 0, 0);
      }
      const int c0 = (2 * wv) * 16 + (lane & 15);
      #pragma unroll
      for (int rr = 0; rr < 4; ++rr){
        const int row = (lane >> 4) * 4 + rr;
        xs[buf * 4128 + row * 258 + c0]      = acc0[rr];
        xs[buf * 4128 + row * 258 + c0 + 16] = acc1[rr];
      }
    };

    uint4 a8[8];
    loadA(0, a8); domfma(a8, 0);
    loadA(1, a8); domfma(a8, 1);
    __syncthreads();

    float cst = 0.0f;
    uint4 pf[8];
    for (int B = 0; B < 128; ++B){
      if (B + 2 < 128) loadA(B + 2, pf);      // issue; consumed after the 16 steps
      const int pb = B & 1;
      for (int s = 0; s < 16; ++s){
        const int t  = B * 16 + s;
        const int tt = dir ? (TL - 1 - t) : t;
        const int cur = t & 1;
        const float4* hv4 = (const float4*)(h2b + cur * 64) + kc * 2;
        const float4 hA = hv4[0], hB = hv4[1];
        float a0 = dot4(wr[0][1], hB, dot4(wr[0][0], hA, 0.f));
        float a1 = dot4(wr[1][1], hB, dot4(wr[1][0], hA, 0.f));
        float a2 = dot4(wr[2][1], hB, dot4(wr[2][0], hA, 0.f));
        float a3 = dot4(wr[3][1], hB, dot4(wr[3][0], hA, 0.f));
        a0 = swz4_add(dpp_xadd<0x4E>(dpp_xadd<0xB1>(a0)));
        a1 = swz4_add(dpp_xadd<0x4E>(dpp_xadd<0xB1>(a1)));
        a2 = swz4_add(dpp_xadd<0x4E>(dpp_xadd<0xB1>(a2)));
        a3 = swz4_add(dpp_xadd<0x4E>(dpp_xadd<0xB1>(a3)));
        if (kc == 0){
          const float* xr = xs + pb * 4128 + s * 258 + u;
          const float ig = sigf(a0 + xr[0]   + bs[0]);
          const float fg = sigf(a1 + xr[64]  + bs[1]);
          const float gg = tanhff(a2 + xr[128] + bs[2]);
          const float og = sigf(a3 + xr[192] + bs[3]);
          cst = fmaf(fg, cst, ig * gg);
          const float h = og * tanhff(cst);
          h2b[(cur ^ 1) * 64 + u] = h;
          o2o[((size_t)bloc * TL + tt) * 128 + dir * 64 + u] = f2bf(h);
        }
        barrier_lgkm();
      }
      if (B + 2 < 128) domfma(pf, pb);        // fills buf pb for block B+2
    }

  } else {
    // ========== L3: H=16; ONE WAVE PER CHAIN, barrier-free. ===============
    // 4 chains/WG (waves 4..7 exit after staging) -> nL3 = a3/2 unchanged.
    // Per-wave: proj via MFMA every 16 steps, accs stay in REGISTERS and are
    // distributed per-step by ds_bpermute using the verified C-layout
    // (row=(lane>>4)*4+rr, col=lane&15). Wih3 staged once in LDS as bf16
    // with 16B XOR swizzle (16-way -> 2-way frag reads). h3 state in LDS,
    // read as 4 uniform (broadcast) b128. No s_barrier in the scan.
    const int i3 = bid - nL1 - nL2;
    const int mm  = lane & 15;
    const int gg4 = lane >> 4;               // gate id (i,f,g,o) for this lane

    unsigned short* wlds = (unsigned short*)smem;   // 32768 B: [dir][64][128] bf16
    float* h3b = (float*)(smem + 32768);            // 4 ch x 2 x 16 f = 512 B
    for (int idx = tid; idx < 8192; idx += 512){
      const float2 v = *(const float2*)(Wih3 + idx * 2);
      const unsigned off = idx * 4u;
      const unsigned sw  = off ^ ((((off >> 8) & 7u)) << 4);
      *(unsigned*)((unsigned char*)wlds + sw) =
          (unsigned)f2bf(v.x) | ((unsigned)f2bf(v.y) << 16);
    }
    if (tid < 128) h3b[tid] = 0.0f;
    __syncthreads();
    if (wv >= 4) return;                      // idle waves exit; no barriers follow

    const int chain = i3 * 4 + wv;
    const int bloc = chain >> 1, dir = chain & 1;
    const unsigned short* o2i = (p3 ? o2r1 : o2r0) + (size_t)bloc * TL * 128;

    const float* WR = Whh3 + dir * 1024 + (gg4 * 16 + mm) * 16;
    const float4 wr0 = *(const float4*)(WR);
    const float4 wr1 = *(const float4*)(WR + 4);
    const float4 wr2 = *(const float4*)(WR + 8);
    const float4 wr3 = *(const float4*)(WR + 12);
    const float bsv = bih3[dir * 64 + gg4 * 16 + mm] + bhh3[dir * 64 + gg4 * 16 + mm];

    float* hme = h3b + wv * 32;

    uint4 a4[4];
    auto loadA3 = [&](int blk){
      const int pt = dir ? (TL - 1 - (blk * 16 + mm)) : (blk * 16 + mm);
      const unsigned short* bptr = o2i + (size_t)pt * 128 + (lane >> 4) * 8;
      #pragma unroll
      for (int Kf = 0; Kf < 4; ++Kf) a4[Kf] = *(const uint4*)(bptr + Kf * 32);
    };
    fx4 ac0, ac1, ac2, ac3;
    auto domfma3 = [&](){
      ac0 = fx4{0.f,0.f,0.f,0.f}; ac1 = fx4{0.f,0.f,0.f,0.f};
      ac2 = fx4{0.f,0.f,0.f,0.f}; ac3 = fx4{0.f,0.f,0.f,0.f};
      #pragma unroll
      for (int Kf = 0; Kf < 4; ++Kf){
        bfx8 av; __builtin_memcpy(&av, &a4[Kf], 16);
        #pragma unroll
        for (int gt = 0; gt < 4; ++gt){
          unsigned boff = dir * 16384u + (unsigned)(gt * 16 + mm) * 256u
                        + (unsigned)(Kf * 32 + (lane >> 4) * 8) * 2u;
          boff ^= ((unsigned)(mm & 7) << 4);
          bfx8 bv; __builtin_memcpy(&bv, (unsigned char*)wlds + boff, 16);
          if (gt == 0) ac0 = __builtin_amdgcn_mfma_f32_16x16x32_bf16(av, bv, ac0, 0,0,0);
          else if (gt == 1) ac1 = __builtin_amdgcn_mfma_f32_16x16x32_bf16(av, bv, ac1, 0,0,0);
          else if (gt == 2) ac2 = __builtin_amdgcn_mfma_f32_16x16x32_bf16(av, bv, ac2, 0,0,0);
          else ac3 = __builtin_amdgcn_mfma_f32_16x16x32_bf16(av, bv, ac3, 0,0,0);
        }
      }
    };

    loadA3(0); domfma3(); loadA3(1);

    float cst = 0.0f, msum = 0.0f;
    for (int B = 0; B < 128; ++B){
      #pragma unroll
      for (int s = 0; s < 16; ++s){
        const int t = B * 16 + s;
        const int cur = t & 1;
        const float* hb = hme + cur * 16;
        const float4 h0 = *(const float4*)(hb);
        const float4 h1 = *(const float4*)(hb + 4);
        const float4 h2 = *(const float4*)(hb + 8);
        const float4 h3v = *(const float4*)(hb + 12);
        const float rec = dot4(wr3, h3v, dot4(wr2, h2, dot4(wr1, h1, dot4(wr0, h0, 0.f))));
        const int src = (s >> 2) * 16 + mm;
        const float p0 = bperm(ac0[s & 3], src);
        const float p1 = bperm(ac1[s & 3], src);
        const float p2 = bperm(ac2[s & 3], src);
        const float p3 = bperm(ac3[s & 3], src);
        const float pj = (gg4 == 0) ? p0 : (gg4 == 1) ? p1 : (gg4 == 2) ? p2 : p3;
        const float pre = rec + pj + bsv;
        const float sg = sigf((gg4 == 2) ? 2.0f * pre : pre);
        const float act = (gg4 == 2) ? fmaf(2.0f, sg, -1.0f) : sg;
        const float gI = bperm(act, mm);
        const float gF = bperm(act, mm + 16);
        const float gG = bperm(act, mm + 32);
        const float gO = bperm(act, mm + 48);
        if (lane < 16){
          cst = fmaf(gF, cst, gI * gG);
          const float h = gO * tanhff(cst);
          hme[(cur ^ 1) * 16 + mm] = h;
          msum += h;
        }
      }
      if (B + 1 < 128){ domfma3(); if (B + 2 < 128) loadA3(B + 2); }
    }
    if (lane < 16) sums[(size_t)(cb3 + bloc) * 32 + dir * 16 + mm] = msum;
  }
}

// ---------------- head: mean (pre-summed) + MLP, one 64-thr WG per batch
__global__ __launch_bounds__(64) void head_kernel(
    const float* __restrict__ sums,
    const float* __restrict__ hW1, const float* __restrict__ hb1,
    const float* __restrict__ hW2, const float* __restrict__ hb2,
    const float* __restrict__ hW3, const float* __restrict__ hb3,
    float* __restrict__ out)
{
  __shared__ float m[32], h1s[64], h2s[16];
  const int tid = threadIdx.x, b = blockIdx.x;
  if (tid < 32) m[tid] = sums[b * 32 + tid] * (1.0f / 2048.0f);
  __syncthreads();
  {
    float a = hb1[tid];
    #pragma unroll
    for (int k = 0; k < 32; ++k) a = fmaf(m[k], hW1[tid * 32 + k], a);
    h1s[tid] = fmaxf(a, 0.0f);
  }
  __syncthreads();
  if (tid < 16){
    float a = hb2[tid];
    #pragma unroll
    for (int k = 0; k < 64; ++k) a = fmaf(h1s[k], hW2[tid * 64 + k], a);
    h2s[tid] = fmaxf(a, 0.0f);
  }
  __syncthreads();
  if (tid < 20){
    float a = hb3[tid];
    #pragma unroll
    for (int k = 0; k < 16; ++k) a = fmaf(h2s[k], hW3[tid * 16 + k], a);
    out[b * 20 + tid] = a;
  }
}

extern "C" void kernel_launch(void* const* d_in, const int* in_sizes, int n_in,
                              void* d_out, int out_size, void* d_ws, size_t ws_size,
                              hipStream_t stream) {
  (void)in_sizes; (void)n_in; (void)out_size;
  const float* x    = (const float*)d_in[0];
  const float* Wih1 = (const float*)d_in[1];
  const float* Whh1 = (const float*)d_in[2];
  const float* bih1 = (const float*)d_in[3];
  const float* bhh1 = (const float*)d_in[4];
  const float* Wih2 = (const float*)d_in[5];
  const float* Whh2 = (const float*)d_in[6];
  const float* bih2 = (const float*)d_in[7];
  const float* bhh2 = (const float*)d_in[8];
  const float* Wih3 = (const float*)d_in[9];
  const float* Whh3 = (const float*)d_in[10];
  const float* bih3 = (const float*)d_in[11];
  const float* bhh3 = (const float*)d_in[12];
  const float* hW1  = (const float*)d_in[13];
  const float* hb1  = (const float*)d_in[14];
  const float* hW2  = (const float*)d_in[15];
  const float* hb2  = (const float*)d_in[16];
  const float* hW3  = (const float*)d_in[17];
  const float* hb3  = (const float*)d_in[18];
  unsigned char* ws = (unsigned char*)d_ws;

  if (ws_size >= 402685952ull) {
    // ===== Tier 1: fully serialized, full-width stages. =====
    unsigned short* h1 = (unsigned short*)ws;
    unsigned short* o2 = (unsigned short*)(ws + 268435456u);
    float* sums = (float*)(ws + 402653184u);
    mega_kernel<<<dim3(512), dim3(512), 0, stream>>>(   // L1: all 512 chains
        512, 0, 0, 0, 0, 0, 0, 0, 0,
        x, Wih1, Whh1, bih1, bhh1, Wih2, Whh2, bih2, bhh2,
        Wih3, Whh3, bih3, bhh3, h1, h1, o2, o2, sums);
    mega_kernel<<<dim3(512), dim3(512), 0, stream>>>(   // L2
        0, 512, 0, 0, 0, 0, 0, 0, 0,
        x, Wih1, Whh1, bih1, bhh1, Wih2, Whh2, bih2, bhh2,
        Wih3, Whh3, bih3, bhh3, h1, h1, o2, o2, sums);
    mega_kernel<<<dim3(128), dim3(512), 0, stream>>>(   // L3: 4 chains/WG
        0, 0, 128, 0, 0, 0, 0, 0, 0,
        x, Wih1, Whh1, bih1, bhh1, Wih2, Whh2, bih2, bhh2,
        Wih3, Whh3, bih3, bhh3, h1, h1, o2, o2, sums);
    head_kernel<<<dim3(256), dim3(64), 0, stream>>>(
        sums, hW1, hb1, hW2, hb2, hW3, hb3, (float*)d_out);
    return;
  }

  // ===== Ring pipeline, capacity graded by ws_size (known bracket:
  // [276.9 MB, 335.6 MB) -> C=88 branch runs). Footprint(C) =
  // C*3,145,728 + 32,768 B. Round-3 proven schedule; nL3 = a3/2 unchanged.
  {
    int cs[5]; int nch; size_t C;
    if (ws_size >= 276856832ull)      { C = 88; nch = 3; cs[0] = 88; cs[1] = 84; cs[2] = 84; }
    else if (ws_size >= 201359360ull) { C = 64; nch = 4; cs[0] = cs[1] = cs[2] = cs[3] = 64; }
    else                              { C = 52; nch = 5; cs[0] = cs[1] = cs[2] = cs[3] = 52; cs[4] = 48; }

    unsigned short* h1r0 = (unsigned short*)ws;
    unsigned short* h1r1 = h1r0 + C * (size_t)TL * 256;
    unsigned short* o2r0 = (unsigned short*)(ws + C * 2097152ull);
    unsigned short* o2r1 = o2r0 + C * (size_t)TL * 128;
    float* sums = (float*)(ws + C * 3145728ull);

    int co[5]; co[0] = 0;
    for (int i = 1; i < nch; ++i) co[i] = co[i - 1] + cs[i - 1];

    for (int k = 0; k < nch + 2; ++k){
      const int a1 = (k < nch) ? cs[k] : 0;
      const int a2 = (k >= 1 && k < nch + 1) ? cs[k - 1] : 0;
      const int a3 = (k >= 2) ? cs[k - 2] : 0;
      const int nL1 = 2 * a1, nL2 = 2 * a2, nL3 = a3 / 2;
      mega_kernel<<<dim3(nL1 + nL2 + nL3), dim3(512), 0, stream>>>(
          nL1, nL2, nL3,
          (k < nch) ? co[k] : 0, (k >= 1 && k < nch + 1) ? co[k - 1] : 0,
          (k >= 2) ? co[k - 2] : 0,
          k & 1, (k + 1) & 1, k & 1,
          x, Wih1, Whh1, bih1, bhh1, Wih2, Whh2, bih2, bhh2,
          Wih3, Whh3, bih3, bhh3, h1r0, h1r1, o2r0, o2r1, sums);
    }
    head_kernel<<<dim3(256), dim3(64), 0, stream>>>(
        sums, hW1, hb1, hW2, hb2, hW3, hb3, (float*)d_out);
  }
}

// Round 9
// 6699.393 us; speedup vs baseline: 3.5598x; 1.0653x over previous
//
#include <hip/hip_runtime.h>
#include <hip/hip_fp16.h>

#define TL 2048

typedef __attribute__((ext_vector_type(8))) short bfx8;
typedef __attribute__((ext_vector_type(4))) float fx4;

__device__ __forceinline__ float sigf(float x){ return __builtin_amdgcn_rcpf(1.0f + __expf(-x)); }
__device__ __forceinline__ float tanhff(float x){ return fmaf(2.0f, sigf(2.0f*x), -1.0f); }

template<int CTRL>
__device__ __forceinline__ float dpp_xadd(float v){
  int s = __builtin_amdgcn_update_dpp(0, __float_as_int(v), CTRL, 0xF, 0xF, true);
  return v + __int_as_float(s);
}
__device__ __forceinline__ float swz4_add(float v){
  int s = __builtin_amdgcn_ds_swizzle(__float_as_int(v), 0x101F);
  return v + __int_as_float(s);
}
__device__ __forceinline__ float bperm(float v, int srclane){
  return __int_as_float(__builtin_amdgcn_ds_bpermute(srclane << 2, __float_as_int(v)));
}
__device__ __forceinline__ unsigned short f2bf(float f){   // RNE fp32->bf16
  unsigned int u = __float_as_uint(f);
  u += 0x7fffu + ((u >> 16) & 1u);
  return (unsigned short)(u >> 16);
}
__device__ __forceinline__ float dot4(float4 a, float4 b, float acc){
  acc = fmaf(a.x, b.x, acc); acc = fmaf(a.y, b.y, acc);
  acc = fmaf(a.z, b.z, acc); acc = fmaf(a.w, b.w, acc);
  return acc;
}
// LDS-only barrier: do NOT drain vmcnt (global h-stores stay in flight).
__device__ __forceinline__ void barrier_lgkm(){
  asm volatile("s_waitcnt lgkmcnt(0)\ns_barrier" ::: "memory");
}
__device__ __forceinline__ bfx8 pack8(const float* p){
  bfx8 r;
  #pragma unroll
  for (int i = 0; i < 8; ++i) r[i] = (short)f2bf(p[i]);
  return r;
}

// Uber-kernel; segments selected per-block by [nL1 | nL2 | nL3]:
//   blockIdx [0,nL1)            : L1 scan (f16-resident weights, fma_mix)
//   blockIdx [nL1,nL1+nL2)      : L2 scan, Wih2 proj via MFMA lookahead
//   blockIdx [nL1+nL2, +nL3)    : L3 scan, ONE WAVE PER CHAIN (barrier-free)
// HISTORY (do not regress):
//  - launch_bounds must stay (512,2): (512,4) caps VGPR at 64 -> spill (r1).
//  - MFMA-batched L1 (r4-r6) is latency-bound at 1 WG/CU. Reverted.
//  - r8: barrier-free 1-wave L3 (-1.2 ms; mids 1948->1510).
//  - r9: L1 weights were NOT register-resident (128 fp32 floats needed >
//    124-reg/2-block budget -> compiler re-loaded from cache every step;
//    explains pk_fma null in r7). Now packed f16 pairs: 128 weights in 64
//    VGPRs, fmaf(half2float(w),h,acc) -> v_fma_mix. f16 err 2^-11 is 8x
//    tighter than the r5/r6-proven-bf16-W path -> absmax unaffected.
__global__ __launch_bounds__(512, 2) void mega_kernel(
    int nL1, int nL2, int nL3, int cb1, int cb2, int cb3, int p1, int p2, int p3,
    const float* __restrict__ x,
    const float* __restrict__ Wih1, const float* __restrict__ Whh1,
    const float* __restrict__ bih1, const float* __restrict__ bhh1,
    const float* __restrict__ Wih2, const float* __restrict__ Whh2,
    const float* __restrict__ bih2, const float* __restrict__ bhh2,
    const float* __restrict__ Wih3, const float* __restrict__ Whh3,
    const float* __restrict__ bih3, const float* __restrict__ bhh3,
    unsigned short* __restrict__ h1r0, unsigned short* __restrict__ h1r1,
    unsigned short* __restrict__ o2r0, unsigned short* __restrict__ o2r1,
    float* __restrict__ sums)
{
  __shared__ __align__(16) unsigned char smem[34816];
  const int tid  = threadIdx.x;
  const int bid  = blockIdx.x;
  const int lane = tid & 63;
  const int wv   = tid >> 6;

  if (bid < nL1){
    // ================= L1: H=128, D=2 folded. WG = one (b,dir) chain. ======
    const int bloc = bid >> 1, dir = bid & 1;
    unsigned short* h1o = p1 ? h1r1 : h1r0;
    const int kc = tid & 3, u = tid >> 2;

    // Weights: 4 gate-rows x 32 K-elems as f16 pairs -> 64 VGPRs, RESIDENT.
    __half2 wh[4][16];
    const float* Wh = Whh1 + dir * 65536;
    #pragma unroll
    for (int g = 0; g < 4; ++g){
      const float* row = Wh + (g * 128 + u) * 128 + kc * 32;
      #pragma unroll
      for (int q = 0; q < 8; ++q){
        const int ro = (q + 2 * kc) & 7;
        const float4 t = *(const float4*)(row + ro * 4);
        wh[g][2 * q]     = __floats2half2_rn(t.x, t.y);
        wh[g][2 * q + 1] = __floats2half2_rn(t.z, t.w);
      }
    }
    float xwA[4], xwB[4], bs[4];
    #pragma unroll
    for (int g = 0; g < 4; ++g){
      const int r = g * 128 + u;
      xwA[g] = Wih1[dir * 1024 + r * 2];
      xwB[g] = Wih1[dir * 1024 + r * 2 + 1];
      bs[g]  = bih1[dir * 512 + r] + bhh1[dir * 512 + r];
    }
    float* xlds = (float*)smem;                  // 4096 f (full x row)
    float* hbuf = (float*)(smem + 16384);        // 2 x 128 f
    {
      const float* xb = x + (size_t)(cb1 + bloc) * (TL * 2);
      for (int idx = tid; idx < TL * 2; idx += 512) xlds[idx] = xb[idx];
    }
    if (tid < 128){ hbuf[tid] = 0.0f; hbuf[128 + tid] = 0.0f; }
    __syncthreads();

    float cst = 0.0f;
    for (int t = 0; t < TL; ++t){
      const int tt  = dir ? (TL - 1 - t) : t;
      const int cur = t & 1;
      const float4* hp = (const float4*)(hbuf + cur * 128) + kc * 8;
      float a0 = 0.f, a1 = 0.f, a2 = 0.f, a3 = 0.f;
      #pragma unroll
      for (int q = 0; q < 8; ++q){
        const float4 hv = hp[(q + 2 * kc) & 7];
        const __half2 w0a = wh[0][2*q], w0b = wh[0][2*q+1];
        const __half2 w1a = wh[1][2*q], w1b = wh[1][2*q+1];
        const __half2 w2a = wh[2][2*q], w2b = wh[2][2*q+1];
        const __half2 w3a = wh[3][2*q], w3b = wh[3][2*q+1];
        a0 = fmaf(__low2float(w0a), hv.x, a0); a0 = fmaf(__high2float(w0a), hv.y, a0);
        a0 = fmaf(__low2float(w0b), hv.z, a0); a0 = fmaf(__high2float(w0b), hv.w, a0);
        a1 = fmaf(__low2float(w1a), hv.x, a1); a1 = fmaf(__high2float(w1a), hv.y, a1);
        a1 = fmaf(__low2float(w1b), hv.z, a1); a1 = fmaf(__high2float(w1b), hv.w, a1);
        a2 = fmaf(__low2float(w2a), hv.x, a2); a2 = fmaf(__high2float(w2a), hv.y, a2);
        a2 = fmaf(__low2float(w2b), hv.z, a2); a2 = fmaf(__high2float(w2b), hv.w, a2);
        a3 = fmaf(__low2float(w3a), hv.x, a3); a3 = fmaf(__high2float(w3a), hv.y, a3);
        a3 = fmaf(__low2float(w3b), hv.z, a3); a3 = fmaf(__high2float(w3b), hv.w, a3);
      }
      a0 = dpp_xadd<0x4E>(dpp_xadd<0xB1>(a0));
      a1 = dpp_xadd<0x4E>(dpp_xadd<0xB1>(a1));
      a2 = dpp_xadd<0x4E>(dpp_xadd<0xB1>(a2));
      a3 = dpp_xadd<0x4E>(dpp_xadd<0xB1>(a3));
      if (kc == 0){
        const float x0 = xlds[tt * 2], x1 = xlds[tt * 2 + 1];
        const float p0 = a0 + fmaf(xwA[0], x0, fmaf(xwB[0], x1, bs[0]));
        const float p1 = a1 + fmaf(xwA[1], x0, fmaf(xwB[1], x1, bs[1]));
        const float p2 = a2 + fmaf(xwA[2], x0, fmaf(xwB[2], x1, bs[2]));
        const float p3 = a3 + fmaf(xwA[3], x0, fmaf(xwB[3], x1, bs[3]));
        const float ig = sigf(p0), fg = sigf(p1), gg = tanhff(p2), og = sigf(p3);
        cst = fmaf(fg, cst, ig * gg);
        const float h = og * tanhff(cst);
        hbuf[(cur ^ 1) * 128 + u] = h;
        h1o[((size_t)bloc * TL + tt) * 256 + dir * 128 + u] = f2bf(h);
      }
      barrier_lgkm();
    }

  } else if (bid < nL1 + nL2){
    // ================= L2: H=64; proj (K=256) via MFMA lookahead. ==========
    const int i2 = bid - nL1;
    const int bloc = i2 >> 1, dir = i2 & 1;
    const unsigned short* h1i = (p2 ? h1r1 : h1r0) + (size_t)bloc * TL * 256;
    unsigned short* o2o = p2 ? o2r1 : o2r0;
    const int kc = tid & 7, u = tid >> 3;

    float4 wr[4][2]; float bs[4];
    const float* WR = Whh2 + dir * 16384;
    #pragma unroll
    for (int tgt = 0; tgt < 4; ++tgt){
      const int row = tgt * 64 + u;
      wr[tgt][0] = *(const float4*)(WR + row * 64 + kc * 8);
      wr[tgt][1] = *(const float4*)(WR + row * 64 + kc * 8 + 4);
      bs[tgt] = bih2[dir * 256 + row] + bhh2[dir * 256 + row];
    }
    bfx8 Bf[2][8];
    const float* WP = Wih2 + dir * 65536;
    #pragma unroll
    for (int ntl = 0; ntl < 2; ++ntl){
      const int n = (2 * wv + ntl) * 16 + (lane & 15);
      #pragma unroll
      for (int Kf = 0; Kf < 8; ++Kf)
        Bf[ntl][Kf] = pack8(WP + n * 256 + Kf * 32 + (lane >> 4) * 8);
    }
    float* xs  = (float*)smem;                   // 2 bufs x 16 x 258 f
    float* h2b = (float*)(smem + 33024);         // 2 x 64 f
    if (tid < 64){ h2b[tid] = 0.0f; h2b[64 + tid] = 0.0f; }

    auto loadA = [&](int blk, uint4* a8){
      const int m  = lane & 15;
      const int pt = dir ? (TL - 1 - (blk * 16 + m)) : (blk * 16 + m);
      const unsigned short* base = h1i + (size_t)pt * 256 + (lane >> 4) * 8;
      #pragma unroll
      for (int Kf = 0; Kf < 8; ++Kf) a8[Kf] = *(const uint4*)(base + Kf * 32);
    };
    auto domfma = [&](uint4* a8, int buf){
      fx4 acc0 = {0.f,0.f,0.f,0.f}, acc1 = {0.f,0.f,0.f,0.f};
      #pragma unroll
      for (int Kf = 0; Kf < 8; ++Kf){
        bfx8 av; __builtin_memcpy(&av, &a8[Kf], 16);
        acc0 = __builtin_amdgcn_mfma_f32_16x16x32_bf16(av, Bf[0][Kf], acc0, 0, 0, 0);
        acc1 = __builtin_amdgcn_mfma_f32_16x16x32_bf16(av, Bf[1][Kf], acc1, 0, 0, 0);
      }
      const int c0 = (2 * wv) * 16 + (lane & 15);
      #pragma unroll
      for (int rr = 0; rr < 4; ++rr){
        const int row = (lane >> 4) * 4 + rr;
        xs[buf * 4128 + row * 258 + c0]      = acc0[rr];
        xs[buf * 4128 + row * 258 + c0 + 16] = acc1[rr];
      }
    };

    uint4 a8[8];
    loadA(0, a8); domfma(a8, 0);
    loadA(1, a8); domfma(a8, 1);
    __syncthreads();

    float cst = 0.0f;
    uint4 pf[8];
    for (int B = 0; B < 128; ++B){
      if (B + 2 < 128) loadA(B + 2, pf);      // issue; consumed after the 16 steps
      const int pb = B & 1;
      for (int s = 0; s < 16; ++s){
        const int t  = B * 16 + s;
        const int tt = dir ? (TL - 1 - t) : t;
        const int cur = t & 1;
        const float4* hv4 = (const float4*)(h2b + cur * 64) + kc * 2;
        const float4 hA = hv4[0], hB = hv4[1];
        float a0 = dot4(wr[0][1], hB, dot4(wr[0][0], hA, 0.f));
        float a1 = dot4(wr[1][1], hB, dot4(wr[1][0], hA, 0.f));
        float a2 = dot4(wr[2][1], hB, dot4(wr[2][0], hA, 0.f));
        float a3 = dot4(wr[3][1], hB, dot4(wr[3][0], hA, 0.f));
        a0 = swz4_add(dpp_xadd<0x4E>(dpp_xadd<0xB1>(a0)));
        a1 = swz4_add(dpp_xadd<0x4E>(dpp_xadd<0xB1>(a1)));
        a2 = swz4_add(dpp_xadd<0x4E>(dpp_xadd<0xB1>(a2)));
        a3 = swz4_add(dpp_xadd<0x4E>(dpp_xadd<0xB1>(a3)));
        if (kc == 0){
          const float* xr = xs + pb * 4128 + s * 258 + u;
          const float ig = sigf(a0 + xr[0]   + bs[0]);
          const float fg = sigf(a1 + xr[64]  + bs[1]);
          const float gg = tanhff(a2 + xr[128] + bs[2]);
          const float og = sigf(a3 + xr[192] + bs[3]);
          cst = fmaf(fg, cst, ig * gg);
          const float h = og * tanhff(cst);
          h2b[(cur ^ 1) * 64 + u] = h;
          o2o[((size_t)bloc * TL + tt) * 128 + dir * 64 + u] = f2bf(h);
        }
        barrier_lgkm();
      }
      if (B + 2 < 128) domfma(pf, pb);        // fills buf pb for block B+2
    }

  } else {
    // ========== L3: H=16; ONE WAVE PER CHAIN, barrier-free (r8). ==========
    const int i3 = bid - nL1 - nL2;
    const int mm  = lane & 15;
    const int gg4 = lane >> 4;               // gate id (i,f,g,o) for this lane

    unsigned short* wlds = (unsigned short*)smem;   // 32768 B: [dir][64][128] bf16
    float* h3b = (float*)(smem + 32768);            // 4 ch x 2 x 16 f = 512 B
    for (int idx = tid; idx < 8192; idx += 512){
      const float2 v = *(const float2*)(Wih3 + idx * 2);
      const unsigned off = idx * 4u;
      const unsigned sw  = off ^ ((((off >> 8) & 7u)) << 4);
      *(unsigned*)((unsigned char*)wlds + sw) =
          (unsigned)f2bf(v.x) | ((unsigned)f2bf(v.y) << 16);
    }
    if (tid < 128) h3b[tid] = 0.0f;
    __syncthreads();
    if (wv >= 4) return;                      // idle waves exit; no barriers follow

    const int chain = i3 * 4 + wv;
    const int bloc = chain >> 1, dir = chain & 1;
    const unsigned short* o2i = (p3 ? o2r1 : o2r0) + (size_t)bloc * TL * 128;

    const float* WR = Whh3 + dir * 1024 + (gg4 * 16 + mm) * 16;
    const float4 wr0 = *(const float4*)(WR);
    const float4 wr1 = *(const float4*)(WR + 4);
    const float4 wr2 = *(const float4*)(WR + 8);
    const float4 wr3 = *(const float4*)(WR + 12);
    const float bsv = bih3[dir * 64 + gg4 * 16 + mm] + bhh3[dir * 64 + gg4 * 16 + mm];

    float* hme = h3b + wv * 32;

    uint4 a4[4];
    auto loadA3 = [&](int blk){
      const int pt = dir ? (TL - 1 - (blk * 16 + mm)) : (blk * 16 + mm);
      const unsigned short* bptr = o2i + (size_t)pt * 128 + (lane >> 4) * 8;
      #pragma unroll
      for (int Kf = 0; Kf < 4; ++Kf) a4[Kf] = *(const uint4*)(bptr + Kf * 32);
    };
    fx4 ac0, ac1, ac2, ac3;
    auto domfma3 = [&](){
      ac0 = fx4{0.f,0.f,0.f,0.f}; ac1 = fx4{0.f,0.f,0.f,0.f};
      ac2 = fx4{0.f,0.f,0.f,0.f}; ac3 = fx4{0.f,0.f,0.f,0.f};
      #pragma unroll
      for (int Kf = 0; Kf < 4; ++Kf){
        bfx8 av; __builtin_memcpy(&av, &a4[Kf], 16);
        #pragma unroll
        for (int gt = 0; gt < 4; ++gt){
          unsigned boff = dir * 16384u + (unsigned)(gt * 16 + mm) * 256u
                        + (unsigned)(Kf * 32 + (lane >> 4) * 8) * 2u;
          boff ^= ((unsigned)(mm & 7) << 4);
          bfx8 bv; __builtin_memcpy(&bv, (unsigned char*)wlds + boff, 16);
          if (gt == 0) ac0 = __builtin_amdgcn_mfma_f32_16x16x32_bf16(av, bv, ac0, 0,0,0);
          else if (gt == 1) ac1 = __builtin_amdgcn_mfma_f32_16x16x32_bf16(av, bv, ac1, 0,0,0);
          else if (gt == 2) ac2 = __builtin_amdgcn_mfma_f32_16x16x32_bf16(av, bv, ac2, 0,0,0);
          else ac3 = __builtin_amdgcn_mfma_f32_16x16x32_bf16(av, bv, ac3, 0,0,0);
        }
      }
    };

    loadA3(0); domfma3(); loadA3(1);

    float cst = 0.0f, msum = 0.0f;
    for (int B = 0; B < 128; ++B){
      #pragma unroll
      for (int s = 0; s < 16; ++s){
        const int t = B * 16 + s;
        const int cur = t & 1;
        const float* hb = hme + cur * 16;
        const float4 h0 = *(const float4*)(hb);
        const float4 h1 = *(const float4*)(hb + 4);
        const float4 h2 = *(const float4*)(hb + 8);
        const float4 h3v = *(const float4*)(hb + 12);
        const float rec = dot4(wr3, h3v, dot4(wr2, h2, dot4(wr1, h1, dot4(wr0, h0, 0.f))));
        const int src = (s >> 2) * 16 + mm;
        const float p0 = bperm(ac0[s & 3], src);
        const float p1 = bperm(ac1[s & 3], src);
        const float p2 = bperm(ac2[s & 3], src);
        const float p3 = bperm(ac3[s & 3], src);
        const float pj = (gg4 == 0) ? p0 : (gg4 == 1) ? p1 : (gg4 == 2) ? p2 : p3;
        const float pre = rec + pj + bsv;
        const float sg = sigf((gg4 == 2) ? 2.0f * pre : pre);
        const float act = (gg4 == 2) ? fmaf(2.0f, sg, -1.0f) : sg;
        const float gI = bperm(act, mm);
        const float gF = bperm(act, mm + 16);
        const float gG = bperm(act, mm + 32);
        const float gO = bperm(act, mm + 48);
        if (lane < 16){
          cst = fmaf(gF, cst, gI * gG);
          const float h = gO * tanhff(cst);
          hme[(cur ^ 1) * 16 + mm] = h;
          msum += h;
        }
      }
      if (B + 1 < 128){ domfma3(); if (B + 2 < 128) loadA3(B + 2); }
    }
    if (lane < 16) sums[(size_t)(cb3 + bloc) * 32 + dir * 16 + mm] = msum;
  }
}

// ---------------- head: mean (pre-summed) + MLP, one 64-thr WG per batch
__global__ __launch_bounds__(64) void head_kernel(
    const float* __restrict__ sums,
    const float* __restrict__ hW1, const float* __restrict__ hb1,
    const float* __restrict__ hW2, const float* __restrict__ hb2,
    const float* __restrict__ hW3, const float* __restrict__ hb3,
    float* __restrict__ out)
{
  __shared__ float m[32], h1s[64], h2s[16];
  const int tid = threadIdx.x, b = blockIdx.x;
  if (tid < 32) m[tid] = sums[b * 32 + tid] * (1.0f / 2048.0f);
  __syncthreads();
  {
    float a = hb1[tid];
    #pragma unroll
    for (int k = 0; k < 32; ++k) a = fmaf(m[k], hW1[tid * 32 + k], a);
    h1s[tid] = fmaxf(a, 0.0f);
  }
  __syncthreads();
  if (tid < 16){
    float a = hb2[tid];
    #pragma unroll
    for (int k = 0; k < 64; ++k) a = fmaf(h1s[k], hW2[tid * 64 + k], a);
    h2s[tid] = fmaxf(a, 0.0f);
  }
  __syncthreads();
  if (tid < 20){
    float a = hb3[tid];
    #pragma unroll
    for (int k = 0; k < 16; ++k) a = fmaf(h2s[k], hW3[tid * 16 + k], a);
    out[b * 20 + tid] = a;
  }
}

extern "C" void kernel_launch(void* const* d_in, const int* in_sizes, int n_in,
                              void* d_out, int out_size, void* d_ws, size_t ws_size,
                              hipStream_t stream) {
  (void)in_sizes; (void)n_in; (void)out_size;
  const float* x    = (const float*)d_in[0];
  const float* Wih1 = (const float*)d_in[1];
  const float* Whh1 = (const float*)d_in[2];
  const float* bih1 = (const float*)d_in[3];
  const float* bhh1 = (const float*)d_in[4];
  const float* Wih2 = (const float*)d_in[5];
  const float* Whh2 = (const float*)d_in[6];
  const float* bih2 = (const float*)d_in[7];
  const float* bhh2 = (const float*)d_in[8];
  const float* Wih3 = (const float*)d_in[9];
  const float* Whh3 = (const float*)d_in[10];
  const float* bih3 = (const float*)d_in[11];
  const float* bhh3 = (const float*)d_in[12];
  const float* hW1  = (const float*)d_in[13];
  const float* hb1  = (const float*)d_in[14];
  const float* hW2  = (const float*)d_in[15];
  const float* hb2  = (const float*)d_in[16];
  const float* hW3  = (const float*)d_in[17];
  const float* hb3  = (const float*)d_in[18];
  unsigned char* ws = (unsigned char*)d_ws;

  if (ws_size >= 402685952ull) {
    // ===== Tier 1: fully serialized, full-width stages. =====
    unsigned short* h1 = (unsigned short*)ws;
    unsigned short* o2 = (unsigned short*)(ws + 268435456u);
    float* sums = (float*)(ws + 402653184u);
    mega_kernel<<<dim3(512), dim3(512), 0, stream>>>(   // L1: all 512 chains
        512, 0, 0, 0, 0, 0, 0, 0, 0,
        x, Wih1, Whh1, bih1, bhh1, Wih2, Whh2, bih2, bhh2,
        Wih3, Whh3, bih3, bhh3, h1, h1, o2, o2, sums);
    mega_kernel<<<dim3(512), dim3(512), 0, stream>>>(   // L2
        0, 512, 0, 0, 0, 0, 0, 0, 0,
        x, Wih1, Whh1, bih1, bhh1, Wih2, Whh2, bih2, bhh2,
        Wih3, Whh3, bih3, bhh3, h1, h1, o2, o2, sums);
    mega_kernel<<<dim3(128), dim3(512), 0, stream>>>(   // L3: 4 chains/WG
        0, 0, 128, 0, 0, 0, 0, 0, 0,
        x, Wih1, Whh1, bih1, bhh1, Wih2, Whh2, bih2, bhh2,
        Wih3, Whh3, bih3, bhh3, h1, h1, o2, o2, sums);
    head_kernel<<<dim3(256), dim3(64), 0, stream>>>(
        sums, hW1, hb1, hW2, hb2, hW3, hb3, (float*)d_out);
    return;
  }

  // ===== Ring pipeline, capacity graded by ws_size (known bracket:
  // [276.9 MB, 335.6 MB) -> C=88 branch runs). Footprint(C) =
  // C*3,145,728 + 32,768 B. Round-3 proven schedule; nL3 = a3/2.
  {
    int cs[5]; int nch; size_t C;
    if (ws_size >= 276856832ull)      { C = 88; nch = 3; cs[0] = 88; cs[1] = 84; cs[2] = 84; }
    else if (ws_size >= 201359360ull) { C = 64; nch = 4; cs[0] = cs[1] = cs[2] = cs[3] = 64; }
    else                              { C = 52; nch = 5; cs[0] = cs[1] = cs[2] = cs[3] = 52; cs[4] = 48; }

    unsigned short* h1r0 = (unsigned short*)ws;
    unsigned short* h1r1 = h1r0 + C * (size_t)TL * 256;
    unsigned short* o2r0 = (unsigned short*)(ws + C * 2097152ull);
    unsigned short* o2r1 = o2r0 + C * (size_t)TL * 128;
    float* sums = (float*)(ws + C * 3145728ull);

    int co[5]; co[0] = 0;
    for (int i = 1; i < nch; ++i) co[i] = co[i - 1] + cs[i - 1];

    for (int k = 0; k < nch + 2; ++k){
      const int a1 = (k < nch) ? cs[k] : 0;
      const int a2 = (k >= 1 && k < nch + 1) ? cs[k - 1] : 0;
      const int a3 = (k >= 2) ? cs[k - 2] : 0;
      const int nL1 = 2 * a1, nL2 = 2 * a2, nL3 = a3 / 2;
      mega_kernel<<<dim3(nL1 + nL2 + nL3), dim3(512), 0, stream>>>(
          nL1, nL2, nL3,
          (k < nch) ? co[k] : 0, (k >= 1 && k < nch + 1) ? co[k - 1] : 0,
          (k >= 2) ? co[k - 2] : 0,
          k & 1, (k + 1) & 1, k & 1,
          x, Wih1, Whh1, bih1, bhh1, Wih2, Whh2, bih2, bhh2,
          Wih3, Whh3, bih3, bhh3, h1r0, h1r1, o2r0, o2r1, sums);
    }
    head_kernel<<<dim3(256), dim3(64), 0, stream>>>(
        sums, hW1, hb1, hW2, hb2, hW3, hb3, (float*)d_out);
  }
}